// Round 3
// baseline (7361.295 us; speedup 1.0000x reference)
//
#include <hip/hip_runtime.h>
#include <math.h>

// ---------------------------------------------------------------------------
// FNO-GRU 2D: B=16, SX=SY=64, W=64 channels, T=20 steps, YH=33, NFREQ=2112.
// Weights stay in natural [i][o][f] layout (f fastest).
// Workspace (~69 MB):
//   h  : [b][c][x][y] float, 4,194,304
//   B0/B1/B2 : spectral float2 buffers, 2,162,688 each, image-major [img][f].
// Dispatches/step: pw2, fifft_r, pw1, fifft_n, yproj.
//
// Round-5: LDS-staged pw kernels (global_load_lds w16, NBUF=2): 193->118 us
// but VALUBusy only 35%, HBM 22%, LDS pipe ~36% -> latency-bound between
// per-step vmcnt(0) drains (__syncthreads after each of 32 steps exposes a
// full L3 round-trip; ~1.4 blocks/CU resident gives no TLP cover).
// Round-7 (this round): T3+T4 counted-vmcnt pipeline. NBUF=4 ring, depth-3
// prefetch; per step: asm s_waitcnt vmcnt(6) [pw2: 3 loads/batch; 2 batches
// stay in flight ACROSS the barrier] -> raw s_barrier -> issue batch s+3 ->
// compute. Tail: vmcnt(3)/vmcnt(0). pw1: vmcnt(4)/(2)/(0). This is the
// m201-verified plain-HIP pattern; never drain vmcnt to 0 in main loop.
//
// NOTE (round-4 post-mortem, still applies): manual software-pipeline VGPR
// arrays spilled (256 VGPR, 1.1 GB scratch writes). Keep accumulators at
// 32 floats; pipeline via LDS ring, not VGPR arrays.
// ---------------------------------------------------------------------------

#define NIMG   1024         // B*W images
#define NFREQ  2112         // 64*33
#define IMGSZ  4096         // 64*64
#define INV_N  (1.0f/4096.0f)

constexpr int brev6(int i) {
    int r = 0;
    for (int b = 0; b < 6; ++b) r |= ((i >> b) & 1) << (5 - b);
    return r;
}

// 64-point complex FFT, fully unrolled radix-2 DIT. DSIGN=-1 fwd, +1 inv.
template <int DSIGN>
__device__ __forceinline__ void fft64(float* xr, float* xi,
                                      const float* cs, const float* sn) {
#pragma unroll
    for (int i = 0; i < 64; ++i) {
        const int j = brev6(i);
        if (j > i) {
            float tr = xr[i]; xr[i] = xr[j]; xr[j] = tr;
            float ti = xi[i]; xi[i] = xi[j]; xi[j] = ti;
        }
    }
#pragma unroll
    for (int s = 1; s <= 6; ++s) {
        const int m = 1 << s, h = m >> 1, step = 64 >> s;
#pragma unroll
        for (int j = 0; j < h; ++j) {
            const int tw = j * step;
            float c = 1.0f, sg = 0.0f;
            if (tw != 0) {
                c  = cs[tw];
                sg = (DSIGN < 0) ? -sn[tw] : sn[tw];
            }
#pragma unroll
            for (int k = j; k < 64; k += m) {
                const int p = k, q = k + h;
                const float vr = xr[q], vi = xi[q];
                float tr, ti;
                if (tw == 0) { tr = vr; ti = vi; }
                else         { tr = c * vr - sg * vi; ti = c * vi + sg * vr; }
                const float ur = xr[p], ui = xi[p];
                xr[p] = ur + tr; xi[p] = ui + ti;
                xr[q] = ur - tr; xi[q] = ui - ti;
            }
        }
    }
}

__device__ __forceinline__ void init_twiddles(float* cs, float* sn, int t) {
    float s, c;
    sincosf(6.28318530717958647692f * (float)t * (1.0f / 64.0f), &s, &c);
    cs[t] = c; sn[t] = s;
}

__device__ __forceinline__ float sigmoidf_(float v) {
    return 1.0f / (1.0f + expf(-v));
}

// ---- shared FFT pass helpers (lds: float2[64*33], row-major [x][k]) -------
__device__ __forceinline__ void ifft_pass_x(const float2* __restrict__ F,
                                            float2* lds, const float* cs,
                                            const float* sn, int t) {
    __syncthreads();
    if (t < 33) {
        float ar[64], ai[64];
#pragma unroll
        for (int kx = 0; kx < 64; ++kx) {
            float2 v = F[kx * 33 + t];
            ar[kx] = v.x; ai[kx] = v.y;
        }
        fft64<1>(ar, ai, cs, sn);
#pragma unroll
        for (int x = 0; x < 64; ++x) lds[x * 33 + t] = make_float2(ar[x], ai[x]);
    }
    __syncthreads();
}

__device__ __forceinline__ void ifft_pass_y(const float2* lds, float* xr,
                                            float* xi, const float* cs,
                                            const float* sn, int t) {
#pragma unroll
    for (int k = 0; k <= 32; ++k) {
        float2 v = lds[t * 33 + k];
        xr[k] = v.x; xi[k] = v.y;
    }
#pragma unroll
    for (int k = 33; k < 64; ++k) {
        float2 v = lds[t * 33 + (64 - k)];
        xr[k] = v.x; xi[k] = -v.y;
    }
    fft64<1>(xr, xi, cs, sn);
}

__device__ __forceinline__ void fwd_pass_y(float* xr, float* xi, float2* lds,
                                           const float* cs, const float* sn,
                                           int t) {
    fft64<-1>(xr, xi, cs, sn);
#pragma unroll
    for (int k = 0; k <= 32; ++k) lds[t * 33 + k] = make_float2(xr[k], xi[k]);
}

__device__ __forceinline__ void fwd_pass_x(const float2* lds,
                                           float2* __restrict__ out,
                                           const float* cs, const float* sn,
                                           int t) {
    __syncthreads();
    if (t < 33) {
        float ar[64], ai[64];
#pragma unroll
        for (int x = 0; x < 64; ++x) {
            float2 v = lds[x * 33 + t];
            ar[x] = v.x; ai[x] = v.y;
        }
        fft64<-1>(ar, ai, cs, sn);
#pragma unroll
        for (int kx = 0; kx < 64; ++kx) out[kx * 33 + t] = make_float2(ar[kx], ai[kx]);
    }
}

// ---------------- h0 = x*Wi[c]+bi[c], then rfft2 -> Hf ---------------------
__global__ __launch_bounds__(64) void k_h0fft(const float* __restrict__ x,
                                              const float* __restrict__ Wi,
                                              const float* __restrict__ bi,
                                              float* __restrict__ h,
                                              float2* __restrict__ Hf) {
    __shared__ float cs[64], sn[64];
    __shared__ float2 lds[64 * 33];
    const int t = threadIdx.x;
    init_twiddles(cs, sn, t);
    __syncthreads();
    const int ib = blockIdx.x;        // b*64+c
    const int c = ib & 63, b = ib >> 6;
    const float wi = Wi[c], bc = bi[c];

    float xr[64], xi[64];
    const float4* xrow = (const float4*)(x + (size_t)b * IMGSZ + t * 64);
    float4* hrow = (float4*)(h + (size_t)ib * IMGSZ + t * 64);
#pragma unroll
    for (int k = 0; k < 16; ++k) {
        float4 v = xrow[k];
        v.x = v.x * wi + bc; v.y = v.y * wi + bc;
        v.z = v.z * wi + bc; v.w = v.w * wi + bc;
        hrow[k] = v;
        xr[4 * k + 0] = v.x; xr[4 * k + 1] = v.y;
        xr[4 * k + 2] = v.z; xr[4 * k + 3] = v.w;
    }
#pragma unroll
    for (int k = 0; k < 64; ++k) xi[k] = 0.0f;
    fwd_pass_y(xr, xi, lds, cs, sn, t);
    fwd_pass_x(lds, Hf + (size_t)ib * NFREQ, cs, sn, t);
}

// ---------------- irfft2(Rf) -> r; rh = sigmoid(r)*h; rfft2(rh) -> RHf -----
__global__ __launch_bounds__(64) void k_fifft_r(const float2* __restrict__ Rf,
                                                const float* __restrict__ h,
                                                float2* __restrict__ RHf) {
    __shared__ float cs[64], sn[64];
    __shared__ float2 lds[64 * 33];
    const int t = threadIdx.x;
    init_twiddles(cs, sn, t);
    const size_t ib = blockIdx.x;
    float xr[64], xi[64];

    ifft_pass_x(Rf + ib * NFREQ, lds, cs, sn, t);
    ifft_pass_y(lds, xr, xi, cs, sn, t);
    const float4* h4 = (const float4*)(h + ib * IMGSZ + t * 64);
#pragma unroll
    for (int k = 0; k < 16; ++k) {
        float4 hv = h4[k];
        xr[4 * k + 0] = sigmoidf_(xr[4 * k + 0] * INV_N) * hv.x;
        xr[4 * k + 1] = sigmoidf_(xr[4 * k + 1] * INV_N) * hv.y;
        xr[4 * k + 2] = sigmoidf_(xr[4 * k + 2] * INV_N) * hv.z;
        xr[4 * k + 3] = sigmoidf_(xr[4 * k + 3] * INV_N) * hv.w;
    }
#pragma unroll
    for (int k = 0; k < 64; ++k) xi[k] = 0.0f;
    fwd_pass_y(xr, xi, lds, cs, sn, t);
    fwd_pass_x(lds, RHf + ib * NFREQ, cs, sn, t);
}

// ---- irfft2(Zf)->z, irfft2(Nf)->n, h=(1-z)h+z*tanh(n); write h + rfft2(h) -
__global__ __launch_bounds__(64) void k_fifft_n(const float2* __restrict__ Nf,
                                                const float2* __restrict__ Zf,
                                                float* __restrict__ h,
                                                float2* __restrict__ Hfn) {
    __shared__ float cs[64], sn[64];
    __shared__ float2 lds[64 * 33];
    __shared__ float zbuf[64 * 64];
    const int t = threadIdx.x;
    init_twiddles(cs, sn, t);
    const size_t ib = blockIdx.x;
    float xr[64], xi[64];

    ifft_pass_x(Zf + ib * NFREQ, lds, cs, sn, t);
    ifft_pass_y(lds, xr, xi, cs, sn, t);
#pragma unroll
    for (int k = 0; k < 64; ++k) zbuf[t * 64 + k] = sigmoidf_(xr[k] * INV_N);

    ifft_pass_x(Nf + ib * NFREQ, lds, cs, sn, t);
    ifft_pass_y(lds, xr, xi, cs, sn, t);
    float4* h4 = (float4*)(h + ib * IMGSZ + t * 64);
    const float4* z4 = (const float4*)(zbuf + t * 64);
#pragma unroll
    for (int k = 0; k < 16; ++k) {
        float4 hv = h4[k];
        float4 zv = z4[k];
        hv.x = (1.0f - zv.x) * hv.x + zv.x * tanhf(xr[4 * k + 0] * INV_N);
        hv.y = (1.0f - zv.y) * hv.y + zv.y * tanhf(xr[4 * k + 1] * INV_N);
        hv.z = (1.0f - zv.z) * hv.z + zv.z * tanhf(xr[4 * k + 2] * INV_N);
        hv.w = (1.0f - zv.w) * hv.w + zv.w * tanhf(xr[4 * k + 3] * INV_N);
        h4[k] = hv;
        xr[4 * k + 0] = hv.x; xr[4 * k + 1] = hv.y;
        xr[4 * k + 2] = hv.z; xr[4 * k + 3] = hv.w;
    }
#pragma unroll
    for (int k = 0; k < 64; ++k) xi[k] = 0.0f;
    fwd_pass_y(xr, xi, lds, cs, sn, t);
    fwd_pass_x(lds, Hfn + ib * NFREQ, cs, sn, t);
}

// ---------------- pointwise complex channel mix ----------------------------
// O[b][o][f] = sum_i H[b][i][f] * w[i][o][f]   (complex)
// grid (66, 8, 2): x = 32-complex-freq tile, y = 8-o group, z = 8-b group.
// thread t: fq = t&7 (4 cf each), og = (t>>3)&7 (o in group), w = t>>6
// (wave = b-pair). NBUF=4 ring, depth-3 prefetch, counted vmcnt:
//   Wl[buf][ki][arr][o*8+fq]  (float4, weights)  -- wave w stages arr=w
//   Hl[buf][ki][b_loc][slot]  (float4 = 2 cf)    -- wave w stages ki=w>>1,
//                                                   b_loc (w&1)*4..+3
// global_load_lds writes wave-uniform base + lane*16; lane l = (o_l*8+fq_l)
// for weights and (b_off*16+slot) for Hf, matching the layouts above.
// Per step: wait vmcnt(6) [2 batches span the barrier] -> s_barrier ->
// issue batch s+3 -> compute. Tail: vmcnt(3), vmcnt(0).
__device__ __forceinline__ void gld_lds16(const void* g, void* l) {
    __builtin_amdgcn_global_load_lds(
        (const __attribute__((address_space(1))) unsigned int*)g,
        (__attribute__((address_space(3))) unsigned int*)l, 16, 0, 0);
}

__device__ __forceinline__ void cmadd4(float (&are)[4], float (&aim)[4],
                                       const float4 hA, const float4 hB,
                                       const float4 wr, const float4 wi) {
    are[0] += hA.x * wr.x - hA.y * wi.x;  aim[0] += hA.x * wi.x + hA.y * wr.x;
    are[1] += hA.z * wr.y - hA.w * wi.y;  aim[1] += hA.z * wi.y + hA.w * wr.y;
    are[2] += hB.x * wr.z - hB.y * wi.z;  aim[2] += hB.x * wi.z + hB.y * wr.z;
    are[3] += hB.z * wr.w - hB.w * wi.w;  aim[3] += hB.z * wi.w + hB.w * wr.w;
}

__global__ __launch_bounds__(256) void k_pw2(const float2* __restrict__ Hf,
                                             const float* __restrict__ wzr,
                                             const float* __restrict__ wzi,
                                             const float* __restrict__ wrr,
                                             const float* __restrict__ wri,
                                             float2* __restrict__ Zf,
                                             float2* __restrict__ Rf) {
    __shared__ float4 Wl[4][2][4][64];   // 32 KB
    __shared__ float4 Hl[4][2][8][16];   // 16 KB
    const int t  = threadIdx.x;
    const int l  = t & 63, w = t >> 6;       // lane, wave
    const int fq = t & 7,  og = (t >> 3) & 7;
    const int o  = blockIdx.y * 8 + og;
    const int b0 = blockIdx.z * 8 + w * 2;
    const int fA = blockIdx.x * 32 + fq * 4;
    const size_t wstep = (size_t)64 * NFREQ;

    // staging source bases (per-lane global addresses)
    const int o_l = l >> 3, fq_l = l & 7;
    const float* wa = (w == 0) ? wzr : (w == 1) ? wzi : (w == 2) ? wrr : wri;
    const float* wsrc = wa + (size_t)(blockIdx.y * 8 + o_l) * NFREQ
                           + blockIdx.x * 32 + fq_l * 4;
    const int ski = w >> 1;                   // Hf ki staged by this wave
    const int sb  = (w & 1) * 4 + (l >> 4);   // local b staged by this lane
    const float2* hsrc = Hf + (size_t)((blockIdx.z * 8 + sb) * 64) * NFREQ
                            + blockIdx.x * 32 + (l & 15) * 2;

#define STAGE2(ii, bf) do {                                                   \
        const int _i0 = 2 * (ii);                                             \
        gld_lds16(wsrc + (size_t)_i0 * wstep,         &Wl[bf][0][w][0]);      \
        gld_lds16(wsrc + (size_t)(_i0 + 1) * wstep,   &Wl[bf][1][w][0]);      \
        gld_lds16(hsrc + (size_t)(_i0 + ski) * NFREQ, &Hl[bf][ski][(w & 1) * 4][0]); \
    } while (0)

    float zre[2][4], zim[2][4], rre[2][4], rim[2][4];
#pragma unroll
    for (int b = 0; b < 2; ++b)
#pragma unroll
        for (int k = 0; k < 4; ++k) {
            zre[b][k] = 0.0f; zim[b][k] = 0.0f;
            rre[b][k] = 0.0f; rim[b][k] = 0.0f;
        }

    // prologue: stage batches 0,1,2 (depth-3)
    STAGE2(0, 0); STAGE2(1, 1); STAGE2(2, 2);

    for (int s = 0; s < 32; ++s) {
        // own batch s retired; batches s+1,s+2 stay in flight across barrier
        if (s < 30)       asm volatile("s_waitcnt vmcnt(6)" ::: "memory");
        else if (s == 30) asm volatile("s_waitcnt vmcnt(3)" ::: "memory");
        else              asm volatile("s_waitcnt vmcnt(0)" ::: "memory");
        __builtin_amdgcn_s_barrier();
        asm volatile("" ::: "memory");       // pin LDS reads below barrier
        if (s < 29) STAGE2(s + 3, (s + 3) & 3);  // overwrites buf read at s-1
        const int buf = s & 3;
#pragma unroll
        for (int ki = 0; ki < 2; ++ki) {
            const float4 vzr = Wl[buf][ki][0][og * 8 + fq];
            const float4 vzi = Wl[buf][ki][1][og * 8 + fq];
            const float4 vrr = Wl[buf][ki][2][og * 8 + fq];
            const float4 vri = Wl[buf][ki][3][og * 8 + fq];
#pragma unroll
            for (int bb = 0; bb < 2; ++bb) {
                const float4 hA = Hl[buf][ki][w * 2 + bb][2 * fq];
                const float4 hB = Hl[buf][ki][w * 2 + bb][2 * fq + 1];
                cmadd4(zre[bb], zim[bb], hA, hB, vzr, vzi);
                cmadd4(rre[bb], rim[bb], hA, hB, vrr, vri);
            }
        }
    }
#undef STAGE2

#pragma unroll
    for (int b = 0; b < 2; ++b) {
        float4* pz = (float4*)(Zf + (size_t)((b0 + b) * 64 + o) * NFREQ + fA);
        float4* pr = (float4*)(Rf + (size_t)((b0 + b) * 64 + o) * NFREQ + fA);
        pz[0] = make_float4(zre[b][0], zim[b][0], zre[b][1], zim[b][1]);
        pz[1] = make_float4(zre[b][2], zim[b][2], zre[b][3], zim[b][3]);
        pr[0] = make_float4(rre[b][0], rim[b][0], rre[b][1], rim[b][1]);
        pr[1] = make_float4(rre[b][2], rim[b][2], rre[b][3], rim[b][3]);
    }
}

__global__ __launch_bounds__(256) void k_pw1(const float2* __restrict__ Hf,
                                             const float* __restrict__ whr,
                                             const float* __restrict__ whi,
                                             float2* __restrict__ Of) {
    __shared__ float4 Wl[4][2][2][64];   // 16 KB
    __shared__ float4 Hl[4][2][8][16];   // 16 KB
    const int t  = threadIdx.x;
    const int l  = t & 63, w = t >> 6;
    const int fq = t & 7,  og = (t >> 3) & 7;
    const int o  = blockIdx.y * 8 + og;
    const int b0 = blockIdx.z * 8 + w * 2;
    const int fA = blockIdx.x * 32 + fq * 4;
    const size_t wstep = (size_t)64 * NFREQ;

    // wave w stages weight (ki=w>>1, arr=w&1) and Hf (ki=w>>1, half=w&1)
    const int o_l = l >> 3, fq_l = l & 7;
    const int ski = w >> 1;
    const float* wa = (w & 1) ? whi : whr;
    const float* wsrc = wa + (size_t)(blockIdx.y * 8 + o_l) * NFREQ
                           + blockIdx.x * 32 + fq_l * 4;
    const int sb  = (w & 1) * 4 + (l >> 4);
    const float2* hsrc = Hf + (size_t)((blockIdx.z * 8 + sb) * 64) * NFREQ
                            + blockIdx.x * 32 + (l & 15) * 2;

#define STAGE1(ii, bf) do {                                                   \
        const int _i0 = 2 * (ii);                                             \
        gld_lds16(wsrc + (size_t)(_i0 + ski) * wstep, &Wl[bf][ski][w & 1][0]); \
        gld_lds16(hsrc + (size_t)(_i0 + ski) * NFREQ, &Hl[bf][ski][(w & 1) * 4][0]); \
    } while (0)

    float cre[2][4], cim[2][4];
#pragma unroll
    for (int b = 0; b < 2; ++b)
#pragma unroll
        for (int k = 0; k < 4; ++k) { cre[b][k] = 0.0f; cim[b][k] = 0.0f; }

    STAGE1(0, 0); STAGE1(1, 1); STAGE1(2, 2);

    for (int s = 0; s < 32; ++s) {
        if (s < 30)       asm volatile("s_waitcnt vmcnt(4)" ::: "memory");
        else if (s == 30) asm volatile("s_waitcnt vmcnt(2)" ::: "memory");
        else              asm volatile("s_waitcnt vmcnt(0)" ::: "memory");
        __builtin_amdgcn_s_barrier();
        asm volatile("" ::: "memory");
        if (s < 29) STAGE1(s + 3, (s + 3) & 3);
        const int buf = s & 3;
#pragma unroll
        for (int ki = 0; ki < 2; ++ki) {
            const float4 vr = Wl[buf][ki][0][og * 8 + fq];
            const float4 vi = Wl[buf][ki][1][og * 8 + fq];
#pragma unroll
            for (int bb = 0; bb < 2; ++bb) {
                const float4 hA = Hl[buf][ki][w * 2 + bb][2 * fq];
                const float4 hB = Hl[buf][ki][w * 2 + bb][2 * fq + 1];
                cmadd4(cre[bb], cim[bb], hA, hB, vr, vi);
            }
        }
    }
#undef STAGE1

#pragma unroll
    for (int b = 0; b < 2; ++b) {
        float4* po = (float4*)(Of + (size_t)((b0 + b) * 64 + o) * NFREQ + fA);
        po[0] = make_float4(cre[b][0], cim[b][0], cre[b][1], cim[b][1]);
        po[1] = make_float4(cre[b][2], cim[b][2], cre[b][3], cim[b][3]);
    }
}

// ---------------- y = h @ Wo + bo, per step --------------------------------
__global__ __launch_bounds__(256) void k_yproj(const float* __restrict__ h,
                                               const float* __restrict__ Wo,
                                               const float* __restrict__ bo,
                                               float* __restrict__ out,
                                               int step) {
    __shared__ float wo[64];
    const int t = threadIdx.x;
    if (t < 64) wo[t] = Wo[t];
    __syncthreads();
    const int b = blockIdx.x >> 4, xg = blockIdx.x & 15;
    const int xx = xg * 4 + (t >> 6), y = t & 63;
    const float* hp = h + (size_t)b * 64 * IMGSZ + xx * 64 + y;
    float acc = bo[0];
#pragma unroll 8
    for (int c = 0; c < 64; ++c) acc += hp[(size_t)c * IMGSZ] * wo[c];
    out[((size_t)b * 20 + step) * IMGSZ + xx * 64 + y] = acc;
}

// ---------------------------------------------------------------------------
extern "C" void kernel_launch(void* const* d_in, const int* in_sizes, int n_in,
                              void* d_out, int out_size, void* d_ws, size_t ws_size,
                              hipStream_t stream) {
    const float* x    = (const float*)d_in[0];
    // d_in[1] = num_time_steps (always 20 per setup_inputs)
    const float* Wi   = (const float*)d_in[2];
    const float* bi   = (const float*)d_in[3];
    const float* Wo   = (const float*)d_in[4];
    const float* bo   = (const float*)d_in[5];
    const float* Wz_r = (const float*)d_in[6];
    const float* Wz_i = (const float*)d_in[7];
    const float* Wr_r = (const float*)d_in[8];
    const float* Wr_i = (const float*)d_in[9];
    const float* Wh_r = (const float*)d_in[10];
    const float* Wh_i = (const float*)d_in[11];

    float* ws = (float*)d_ws;
    float* h = ws;                              // 4,194,304 floats
    float2* B0 = (float2*)(ws + 4194304);       // 2,162,688 float2 each
    float2* B1 = B0 + 2162688;
    float2* B2 = B1 + 2162688;
    float* outp = (float*)d_out;

    k_h0fft<<<NIMG, 64, 0, stream>>>(x, Wi, bi, h, B0);   // h0, Hf -> B0

    for (int t = 0; t < 20; ++t) {
        k_pw2<<<dim3(66, 8, 2), 256, 0, stream>>>(B0, Wz_r, Wz_i, Wr_r, Wr_i,
                                                  B1, B2);  // Zf->B1 Rf->B2
        k_fifft_r<<<NIMG, 64, 0, stream>>>(B2, h, B2);      // RHf -> B2
        k_pw1<<<dim3(66, 8, 2), 256, 0, stream>>>(B2, Wh_r, Wh_i, B0); // Nf->B0
        k_fifft_n<<<NIMG, 64, 0, stream>>>(B0, B1, h, B0);  // h, Hf_next -> B0
        k_yproj<<<256, 256, 0, stream>>>(h, Wo, bo, outp, t);
    }
}

// Round 4
// 4700.149 us; speedup vs baseline: 1.5662x; 1.5662x over previous
//
#include <hip/hip_runtime.h>
#include <math.h>

// ---------------------------------------------------------------------------
// FNO-GRU 2D: B=16, SX=SY=64, W=64 channels, T=20 steps, YH=33, NFREQ=2112.
// Weights stay in natural [i][o][f] layout (f fastest).
// Workspace (~69 MB):
//   h  : [b][c][x][y] float, 4,194,304
//   B0/B1/B2 : spectral float2 buffers, 2,162,688 each, image-major [img][f].
// Dispatches/step: pw2, fifft_r, pw1, fifft_n, yproj.
//
// Round-5: LDS-staged pw kernels (global_load_lds w16, NBUF=2): 193->118 us.
// Round-7 POST-MORTEM: counted-vmcnt + raw s_barrier ring (T3/T4 graft)
// REGRESSED 4491->7361 us with one 19.7 ms pw2 dispatch at 3% occupancy --
// hipcc scheduling around hand-waitcnt is fragile (guide m131-m141/m152).
// DO NOT reintroduce manual vmcnt here. Reverted to __syncthreads NBUF=2.
// Round-8 (this round): round-2 model showed latency-bound (VALU 35%, LDS
// 23%, HBM 22%, nothing saturated) with only ~4 blocks/CU. Fix TLP instead:
// grid z 2->4 (1 b per wave, 2112 blocks = 8.25/CU), accumulators 32->16
// floats, LDS 24->20 KB, __launch_bounds__(256,8) to force VGPR<=64 so all
// 8 blocks/CU are resident. Drains unchanged but now overlapped by 2x TLP.
//
// NOTE (round-4 post-mortem, still applies): manual software-pipeline VGPR
// arrays spilled (256 VGPR, 1.1 GB scratch writes). Keep accumulators small;
// pipeline via LDS double-buffer only.
// ---------------------------------------------------------------------------

#define NIMG   1024         // B*W images
#define NFREQ  2112         // 64*33
#define IMGSZ  4096         // 64*64
#define INV_N  (1.0f/4096.0f)

constexpr int brev6(int i) {
    int r = 0;
    for (int b = 0; b < 6; ++b) r |= ((i >> b) & 1) << (5 - b);
    return r;
}

// 64-point complex FFT, fully unrolled radix-2 DIT. DSIGN=-1 fwd, +1 inv.
template <int DSIGN>
__device__ __forceinline__ void fft64(float* xr, float* xi,
                                      const float* cs, const float* sn) {
#pragma unroll
    for (int i = 0; i < 64; ++i) {
        const int j = brev6(i);
        if (j > i) {
            float tr = xr[i]; xr[i] = xr[j]; xr[j] = tr;
            float ti = xi[i]; xi[i] = xi[j]; xi[j] = ti;
        }
    }
#pragma unroll
    for (int s = 1; s <= 6; ++s) {
        const int m = 1 << s, h = m >> 1, step = 64 >> s;
#pragma unroll
        for (int j = 0; j < h; ++j) {
            const int tw = j * step;
            float c = 1.0f, sg = 0.0f;
            if (tw != 0) {
                c  = cs[tw];
                sg = (DSIGN < 0) ? -sn[tw] : sn[tw];
            }
#pragma unroll
            for (int k = j; k < 64; k += m) {
                const int p = k, q = k + h;
                const float vr = xr[q], vi = xi[q];
                float tr, ti;
                if (tw == 0) { tr = vr; ti = vi; }
                else         { tr = c * vr - sg * vi; ti = c * vi + sg * vr; }
                const float ur = xr[p], ui = xi[p];
                xr[p] = ur + tr; xi[p] = ui + ti;
                xr[q] = ur - tr; xi[q] = ui - ti;
            }
        }
    }
}

__device__ __forceinline__ void init_twiddles(float* cs, float* sn, int t) {
    float s, c;
    sincosf(6.28318530717958647692f * (float)t * (1.0f / 64.0f), &s, &c);
    cs[t] = c; sn[t] = s;
}

__device__ __forceinline__ float sigmoidf_(float v) {
    return 1.0f / (1.0f + expf(-v));
}

// ---- shared FFT pass helpers (lds: float2[64*33], row-major [x][k]) -------
__device__ __forceinline__ void ifft_pass_x(const float2* __restrict__ F,
                                            float2* lds, const float* cs,
                                            const float* sn, int t) {
    __syncthreads();
    if (t < 33) {
        float ar[64], ai[64];
#pragma unroll
        for (int kx = 0; kx < 64; ++kx) {
            float2 v = F[kx * 33 + t];
            ar[kx] = v.x; ai[kx] = v.y;
        }
        fft64<1>(ar, ai, cs, sn);
#pragma unroll
        for (int x = 0; x < 64; ++x) lds[x * 33 + t] = make_float2(ar[x], ai[x]);
    }
    __syncthreads();
}

__device__ __forceinline__ void ifft_pass_y(const float2* lds, float* xr,
                                            float* xi, const float* cs,
                                            const float* sn, int t) {
#pragma unroll
    for (int k = 0; k <= 32; ++k) {
        float2 v = lds[t * 33 + k];
        xr[k] = v.x; xi[k] = v.y;
    }
#pragma unroll
    for (int k = 33; k < 64; ++k) {
        float2 v = lds[t * 33 + (64 - k)];
        xr[k] = v.x; xi[k] = -v.y;
    }
    fft64<1>(xr, xi, cs, sn);
}

__device__ __forceinline__ void fwd_pass_y(float* xr, float* xi, float2* lds,
                                           const float* cs, const float* sn,
                                           int t) {
    fft64<-1>(xr, xi, cs, sn);
#pragma unroll
    for (int k = 0; k <= 32; ++k) lds[t * 33 + k] = make_float2(xr[k], xi[k]);
}

__device__ __forceinline__ void fwd_pass_x(const float2* lds,
                                           float2* __restrict__ out,
                                           const float* cs, const float* sn,
                                           int t) {
    __syncthreads();
    if (t < 33) {
        float ar[64], ai[64];
#pragma unroll
        for (int x = 0; x < 64; ++x) {
            float2 v = lds[x * 33 + t];
            ar[x] = v.x; ai[x] = v.y;
        }
        fft64<-1>(ar, ai, cs, sn);
#pragma unroll
        for (int kx = 0; kx < 64; ++kx) out[kx * 33 + t] = make_float2(ar[kx], ai[kx]);
    }
}

// ---------------- h0 = x*Wi[c]+bi[c], then rfft2 -> Hf ---------------------
__global__ __launch_bounds__(64) void k_h0fft(const float* __restrict__ x,
                                              const float* __restrict__ Wi,
                                              const float* __restrict__ bi,
                                              float* __restrict__ h,
                                              float2* __restrict__ Hf) {
    __shared__ float cs[64], sn[64];
    __shared__ float2 lds[64 * 33];
    const int t = threadIdx.x;
    init_twiddles(cs, sn, t);
    __syncthreads();
    const int ib = blockIdx.x;        // b*64+c
    const int c = ib & 63, b = ib >> 6;
    const float wi = Wi[c], bc = bi[c];

    float xr[64], xi[64];
    const float4* xrow = (const float4*)(x + (size_t)b * IMGSZ + t * 64);
    float4* hrow = (float4*)(h + (size_t)ib * IMGSZ + t * 64);
#pragma unroll
    for (int k = 0; k < 16; ++k) {
        float4 v = xrow[k];
        v.x = v.x * wi + bc; v.y = v.y * wi + bc;
        v.z = v.z * wi + bc; v.w = v.w * wi + bc;
        hrow[k] = v;
        xr[4 * k + 0] = v.x; xr[4 * k + 1] = v.y;
        xr[4 * k + 2] = v.z; xr[4 * k + 3] = v.w;
    }
#pragma unroll
    for (int k = 0; k < 64; ++k) xi[k] = 0.0f;
    fwd_pass_y(xr, xi, lds, cs, sn, t);
    fwd_pass_x(lds, Hf + (size_t)ib * NFREQ, cs, sn, t);
}

// ---------------- irfft2(Rf) -> r; rh = sigmoid(r)*h; rfft2(rh) -> RHf -----
__global__ __launch_bounds__(64) void k_fifft_r(const float2* __restrict__ Rf,
                                                const float* __restrict__ h,
                                                float2* __restrict__ RHf) {
    __shared__ float cs[64], sn[64];
    __shared__ float2 lds[64 * 33];
    const int t = threadIdx.x;
    init_twiddles(cs, sn, t);
    const size_t ib = blockIdx.x;
    float xr[64], xi[64];

    ifft_pass_x(Rf + ib * NFREQ, lds, cs, sn, t);
    ifft_pass_y(lds, xr, xi, cs, sn, t);
    const float4* h4 = (const float4*)(h + ib * IMGSZ + t * 64);
#pragma unroll
    for (int k = 0; k < 16; ++k) {
        float4 hv = h4[k];
        xr[4 * k + 0] = sigmoidf_(xr[4 * k + 0] * INV_N) * hv.x;
        xr[4 * k + 1] = sigmoidf_(xr[4 * k + 1] * INV_N) * hv.y;
        xr[4 * k + 2] = sigmoidf_(xr[4 * k + 2] * INV_N) * hv.z;
        xr[4 * k + 3] = sigmoidf_(xr[4 * k + 3] * INV_N) * hv.w;
    }
#pragma unroll
    for (int k = 0; k < 64; ++k) xi[k] = 0.0f;
    fwd_pass_y(xr, xi, lds, cs, sn, t);
    fwd_pass_x(lds, RHf + ib * NFREQ, cs, sn, t);
}

// ---- irfft2(Zf)->z, irfft2(Nf)->n, h=(1-z)h+z*tanh(n); write h + rfft2(h) -
__global__ __launch_bounds__(64) void k_fifft_n(const float2* __restrict__ Nf,
                                                const float2* __restrict__ Zf,
                                                float* __restrict__ h,
                                                float2* __restrict__ Hfn) {
    __shared__ float cs[64], sn[64];
    __shared__ float2 lds[64 * 33];
    __shared__ float zbuf[64 * 64];
    const int t = threadIdx.x;
    init_twiddles(cs, sn, t);
    const size_t ib = blockIdx.x;
    float xr[64], xi[64];

    ifft_pass_x(Zf + ib * NFREQ, lds, cs, sn, t);
    ifft_pass_y(lds, xr, xi, cs, sn, t);
#pragma unroll
    for (int k = 0; k < 64; ++k) zbuf[t * 64 + k] = sigmoidf_(xr[k] * INV_N);

    ifft_pass_x(Nf + ib * NFREQ, lds, cs, sn, t);
    ifft_pass_y(lds, xr, xi, cs, sn, t);
    float4* h4 = (float4*)(h + ib * IMGSZ + t * 64);
    const float4* z4 = (const float4*)(zbuf + t * 64);
#pragma unroll
    for (int k = 0; k < 16; ++k) {
        float4 hv = h4[k];
        float4 zv = z4[k];
        hv.x = (1.0f - zv.x) * hv.x + zv.x * tanhf(xr[4 * k + 0] * INV_N);
        hv.y = (1.0f - zv.y) * hv.y + zv.y * tanhf(xr[4 * k + 1] * INV_N);
        hv.z = (1.0f - zv.z) * hv.z + zv.z * tanhf(xr[4 * k + 2] * INV_N);
        hv.w = (1.0f - zv.w) * hv.w + zv.w * tanhf(xr[4 * k + 3] * INV_N);
        h4[k] = hv;
        xr[4 * k + 0] = hv.x; xr[4 * k + 1] = hv.y;
        xr[4 * k + 2] = hv.z; xr[4 * k + 3] = hv.w;
    }
#pragma unroll
    for (int k = 0; k < 64; ++k) xi[k] = 0.0f;
    fwd_pass_y(xr, xi, lds, cs, sn, t);
    fwd_pass_x(lds, Hfn + ib * NFREQ, cs, sn, t);
}

// ---------------- pointwise complex channel mix ----------------------------
// O[b][o][f] = sum_i H[b][i][f] * w[i][o][f]   (complex)
// grid (66, 8, 4): x = 32-complex-freq tile, y = 8-o group, z = 4-b group.
// thread t: fq = t&7 (4 cf each), og = (t>>3)&7, wave w = t>>6 owns ONE b
// (b = z*4 + w). NBUF=2 LDS double-buffer, KI=2 i's per stage step:
//   Wl[buf][ki][arr][o*8+fq]  (float4)  -- wave w stages arr=w (pw2)
//   Hl[buf][ki][b_loc][slot]  (float4 = 2 cf) -- b_loc = l>>4, slot = l&15;
//                                staged by waves 0,1 (ki = w) in pw2.
// global_load_lds writes wave-uniform base + lane*16; lane l = (o_l*8+fq_l)
// for weights and (b_loc*16+slot) for Hf, matching the layouts above.
// Wave-asymmetric load counts are safe: __syncthreads fully drains vmcnt.
__device__ __forceinline__ void gld_lds16(const void* g, void* l) {
    __builtin_amdgcn_global_load_lds(
        (const __attribute__((address_space(1))) unsigned int*)g,
        (__attribute__((address_space(3))) unsigned int*)l, 16, 0, 0);
}

__device__ __forceinline__ void cmadd4(float (&are)[4], float (&aim)[4],
                                       const float4 hA, const float4 hB,
                                       const float4 wr, const float4 wi) {
    are[0] += hA.x * wr.x - hA.y * wi.x;  aim[0] += hA.x * wi.x + hA.y * wr.x;
    are[1] += hA.z * wr.y - hA.w * wi.y;  aim[1] += hA.z * wi.y + hA.w * wr.y;
    are[2] += hB.x * wr.z - hB.y * wi.z;  aim[2] += hB.x * wi.z + hB.y * wr.z;
    are[3] += hB.z * wr.w - hB.w * wi.w;  aim[3] += hB.z * wi.w + hB.w * wr.w;
}

__global__ __launch_bounds__(256, 8) void k_pw2(const float2* __restrict__ Hf,
                                                const float* __restrict__ wzr,
                                                const float* __restrict__ wzi,
                                                const float* __restrict__ wrr,
                                                const float* __restrict__ wri,
                                                float2* __restrict__ Zf,
                                                float2* __restrict__ Rf) {
    __shared__ float4 Wl[2][2][4][64];   // 16 KB
    __shared__ float4 Hl[2][2][4][16];   //  4 KB
    const int t  = threadIdx.x;
    const int l  = t & 63, w = t >> 6;       // lane, wave (= local b)
    const int fq = t & 7,  og = (t >> 3) & 7;
    const int o  = blockIdx.y * 8 + og;
    const int gb = blockIdx.z * 4 + w;       // global b for this wave
    const int fA = blockIdx.x * 32 + fq * 4;
    const size_t wstep = (size_t)64 * NFREQ;

    // staging source bases (per-lane global addresses)
    const int o_l = l >> 3, fq_l = l & 7;
    const float* wa = (w == 0) ? wzr : (w == 1) ? wzi : (w == 2) ? wrr : wri;
    const float* wsrc = wa + (size_t)(blockIdx.y * 8 + o_l) * NFREQ
                           + blockIdx.x * 32 + fq_l * 4;
    // Hf staging: lane l covers b_loc = l>>4, slot = l&15 (2 cf per slot)
    const float2* hsrc = Hf + (size_t)((blockIdx.z * 4 + (l >> 4)) * 64) * NFREQ
                            + blockIdx.x * 32 + (l & 15) * 2;

#define STAGE2(ii, bf) do {                                                    \
        const int _i0 = 2 * (ii);                                              \
        gld_lds16(wsrc + (size_t)_i0 * wstep,       &Wl[bf][0][w][0]);         \
        gld_lds16(wsrc + (size_t)(_i0 + 1) * wstep, &Wl[bf][1][w][0]);         \
        if (w < 2)                                                             \
            gld_lds16(hsrc + (size_t)(_i0 + w) * NFREQ, &Hl[bf][w][0][0]);     \
    } while (0)

    float zre[4], zim[4], rre[4], rim[4];
#pragma unroll
    for (int k = 0; k < 4; ++k) {
        zre[k] = 0.0f; zim[k] = 0.0f; rre[k] = 0.0f; rim[k] = 0.0f;
    }

    STAGE2(0, 0);
    __syncthreads();

    for (int s = 0; s < 32; ++s) {
        const int buf = s & 1;
        if (s < 31) STAGE2(s + 1, buf ^ 1);
#pragma unroll
        for (int ki = 0; ki < 2; ++ki) {
            const float4 vzr = Wl[buf][ki][0][og * 8 + fq];
            const float4 vzi = Wl[buf][ki][1][og * 8 + fq];
            const float4 vrr = Wl[buf][ki][2][og * 8 + fq];
            const float4 vri = Wl[buf][ki][3][og * 8 + fq];
            const float4 hA  = Hl[buf][ki][w][2 * fq];
            const float4 hB  = Hl[buf][ki][w][2 * fq + 1];
            cmadd4(zre, zim, hA, hB, vzr, vzi);
            cmadd4(rre, rim, hA, hB, vrr, vri);
        }
        __syncthreads();
    }
#undef STAGE2

    float4* pz = (float4*)(Zf + (size_t)(gb * 64 + o) * NFREQ + fA);
    float4* pr = (float4*)(Rf + (size_t)(gb * 64 + o) * NFREQ + fA);
    pz[0] = make_float4(zre[0], zim[0], zre[1], zim[1]);
    pz[1] = make_float4(zre[2], zim[2], zre[3], zim[3]);
    pr[0] = make_float4(rre[0], rim[0], rre[1], rim[1]);
    pr[1] = make_float4(rre[2], rim[2], rre[3], rim[3]);
}

__global__ __launch_bounds__(256, 8) void k_pw1(const float2* __restrict__ Hf,
                                                const float* __restrict__ whr,
                                                const float* __restrict__ whi,
                                                float2* __restrict__ Of) {
    __shared__ float4 Wl[2][2][2][64];   // 8 KB
    __shared__ float4 Hl[2][2][4][16];   // 4 KB
    const int t  = threadIdx.x;
    const int l  = t & 63, w = t >> 6;
    const int fq = t & 7,  og = (t >> 3) & 7;
    const int o  = blockIdx.y * 8 + og;
    const int gb = blockIdx.z * 4 + w;
    const int fA = blockIdx.x * 32 + fq * 4;
    const size_t wstep = (size_t)64 * NFREQ;

    // wave w stages weight (ki=w>>1, arr=w&1); waves 2,3 stage Hf (ki=w&1)
    const int o_l = l >> 3, fq_l = l & 7;
    const int wki = w >> 1, warr = w & 1;
    const float* wa = warr ? whi : whr;
    const float* wsrc = wa + (size_t)(blockIdx.y * 8 + o_l) * NFREQ
                           + blockIdx.x * 32 + fq_l * 4;
    const float2* hsrc = Hf + (size_t)((blockIdx.z * 4 + (l >> 4)) * 64) * NFREQ
                            + blockIdx.x * 32 + (l & 15) * 2;

#define STAGE1(ii, bf) do {                                                    \
        const int _i0 = 2 * (ii);                                              \
        gld_lds16(wsrc + (size_t)(_i0 + wki) * wstep, &Wl[bf][wki][warr][0]);  \
        if (w >= 2)                                                            \
            gld_lds16(hsrc + (size_t)(_i0 + (w & 1)) * NFREQ,                  \
                      &Hl[bf][w & 1][0][0]);                                   \
    } while (0)

    float cre[4], cim[4];
#pragma unroll
    for (int k = 0; k < 4; ++k) { cre[k] = 0.0f; cim[k] = 0.0f; }

    STAGE1(0, 0);
    __syncthreads();

    for (int s = 0; s < 32; ++s) {
        const int buf = s & 1;
        if (s < 31) STAGE1(s + 1, buf ^ 1);
#pragma unroll
        for (int ki = 0; ki < 2; ++ki) {
            const float4 vr = Wl[buf][ki][0][og * 8 + fq];
            const float4 vi = Wl[buf][ki][1][og * 8 + fq];
            const float4 hA = Hl[buf][ki][w][2 * fq];
            const float4 hB = Hl[buf][ki][w][2 * fq + 1];
            cmadd4(cre, cim, hA, hB, vr, vi);
        }
        __syncthreads();
    }
#undef STAGE1

    float4* po = (float4*)(Of + (size_t)(gb * 64 + o) * NFREQ + fA);
    po[0] = make_float4(cre[0], cim[0], cre[1], cim[1]);
    po[1] = make_float4(cre[2], cim[2], cre[3], cim[3]);
}

// ---------------- y = h @ Wo + bo, per step --------------------------------
__global__ __launch_bounds__(256) void k_yproj(const float* __restrict__ h,
                                               const float* __restrict__ Wo,
                                               const float* __restrict__ bo,
                                               float* __restrict__ out,
                                               int step) {
    __shared__ float wo[64];
    const int t = threadIdx.x;
    if (t < 64) wo[t] = Wo[t];
    __syncthreads();
    const int b = blockIdx.x >> 4, xg = blockIdx.x & 15;
    const int xx = xg * 4 + (t >> 6), y = t & 63;
    const float* hp = h + (size_t)b * 64 * IMGSZ + xx * 64 + y;
    float acc = bo[0];
#pragma unroll 8
    for (int c = 0; c < 64; ++c) acc += hp[(size_t)c * IMGSZ] * wo[c];
    out[((size_t)b * 20 + step) * IMGSZ + xx * 64 + y] = acc;
}

// ---------------------------------------------------------------------------
extern "C" void kernel_launch(void* const* d_in, const int* in_sizes, int n_in,
                              void* d_out, int out_size, void* d_ws, size_t ws_size,
                              hipStream_t stream) {
    const float* x    = (const float*)d_in[0];
    // d_in[1] = num_time_steps (always 20 per setup_inputs)
    const float* Wi   = (const float*)d_in[2];
    const float* bi   = (const float*)d_in[3];
    const float* Wo   = (const float*)d_in[4];
    const float* bo   = (const float*)d_in[5];
    const float* Wz_r = (const float*)d_in[6];
    const float* Wz_i = (const float*)d_in[7];
    const float* Wr_r = (const float*)d_in[8];
    const float* Wr_i = (const float*)d_in[9];
    const float* Wh_r = (const float*)d_in[10];
    const float* Wh_i = (const float*)d_in[11];

    float* ws = (float*)d_ws;
    float* h = ws;                              // 4,194,304 floats
    float2* B0 = (float2*)(ws + 4194304);       // 2,162,688 float2 each
    float2* B1 = B0 + 2162688;
    float2* B2 = B1 + 2162688;
    float* outp = (float*)d_out;

    k_h0fft<<<NIMG, 64, 0, stream>>>(x, Wi, bi, h, B0);   // h0, Hf -> B0

    for (int t = 0; t < 20; ++t) {
        k_pw2<<<dim3(66, 8, 4), 256, 0, stream>>>(B0, Wz_r, Wz_i, Wr_r, Wr_i,
                                                  B1, B2);  // Zf->B1 Rf->B2
        k_fifft_r<<<NIMG, 64, 0, stream>>>(B2, h, B2);      // RHf -> B2
        k_pw1<<<dim3(66, 8, 4), 256, 0, stream>>>(B2, Wh_r, Wh_i, B0); // Nf->B0
        k_fifft_n<<<NIMG, 64, 0, stream>>>(B0, B1, h, B0);  // h, Hf_next -> B0
        k_yproj<<<256, 256, 0, stream>>>(h, Wo, bo, outp, t);
    }
}

// Round 5
// 4552.920 us; speedup vs baseline: 1.6168x; 1.0323x over previous
//
#include <hip/hip_runtime.h>
#include <math.h>

// ---------------------------------------------------------------------------
// FNO-GRU 2D: B=16, SX=SY=64, W=64 channels, T=20 steps, YH=33, NFREQ=2112.
// Weights stay in natural [i][o][f] layout (f fastest).
// Workspace (~69 MB):
//   h  : [b][c][x][y] float, 4,194,304
//   B0/B1/B2 : spectral float2 buffers, 2,162,688 each, image-major [img][f].
// Dispatches/step: pw2, fifft_r, pw1, fifft_n, yproj.
//
// Round-7 POST-MORTEM: counted-vmcnt + raw s_barrier REGRESSED (19.7 ms
// pathological dispatch). DO NOT reintroduce manual vmcnt/s_barrier.
// Round-8 POST-MORTEM: 1-b-per-wave + occupancy 65% was NEUTRAL (110 us):
// every wave reads the same weight tile -> 6 ds_read_b128 per 64 FMA ->
// LDS read pipe floor alone = 152k cyc/CU = 63 us. Occupancy can't fix a
// pipe-throughput floor.
// Round-9 (this round): back to 2-b-per-thread (round-2 verified map,
// halves LDS reads per FMA: 8 reads / 128 FMA) + KI=4 per stage step (16
// barriers instead of 32; per-step compute ~1400 cyc >= ~900 cyc load
// latency so the __syncthreads vmcnt drain is mostly covered). LDS 48 KB,
// 3 blocks/CU. Sync structure stays plain __syncthreads NBUF=2.
// LDS floor: 4.125 blk x 4 waves x 64 i x 8 reads x 12 cyc = 101k cyc
// = 42 us -> predict pw2 50-62 us.
//
// NOTE (round-4 post-mortem, still applies): manual software-pipeline VGPR
// arrays spilled. Keep accumulators at 32 floats; pipeline via LDS only.
// ---------------------------------------------------------------------------

#define NIMG   1024         // B*W images
#define NFREQ  2112         // 64*33
#define IMGSZ  4096         // 64*64
#define INV_N  (1.0f/4096.0f)

constexpr int brev6(int i) {
    int r = 0;
    for (int b = 0; b < 6; ++b) r |= ((i >> b) & 1) << (5 - b);
    return r;
}

// 64-point complex FFT, fully unrolled radix-2 DIT. DSIGN=-1 fwd, +1 inv.
template <int DSIGN>
__device__ __forceinline__ void fft64(float* xr, float* xi,
                                      const float* cs, const float* sn) {
#pragma unroll
    for (int i = 0; i < 64; ++i) {
        const int j = brev6(i);
        if (j > i) {
            float tr = xr[i]; xr[i] = xr[j]; xr[j] = tr;
            float ti = xi[i]; xi[i] = xi[j]; xi[j] = ti;
        }
    }
#pragma unroll
    for (int s = 1; s <= 6; ++s) {
        const int m = 1 << s, h = m >> 1, step = 64 >> s;
#pragma unroll
        for (int j = 0; j < h; ++j) {
            const int tw = j * step;
            float c = 1.0f, sg = 0.0f;
            if (tw != 0) {
                c  = cs[tw];
                sg = (DSIGN < 0) ? -sn[tw] : sn[tw];
            }
#pragma unroll
            for (int k = j; k < 64; k += m) {
                const int p = k, q = k + h;
                const float vr = xr[q], vi = xi[q];
                float tr, ti;
                if (tw == 0) { tr = vr; ti = vi; }
                else         { tr = c * vr - sg * vi; ti = c * vi + sg * vr; }
                const float ur = xr[p], ui = xi[p];
                xr[p] = ur + tr; xi[p] = ui + ti;
                xr[q] = ur - tr; xi[q] = ui - ti;
            }
        }
    }
}

__device__ __forceinline__ void init_twiddles(float* cs, float* sn, int t) {
    float s, c;
    sincosf(6.28318530717958647692f * (float)t * (1.0f / 64.0f), &s, &c);
    cs[t] = c; sn[t] = s;
}

__device__ __forceinline__ float sigmoidf_(float v) {
    return 1.0f / (1.0f + expf(-v));
}

// ---- shared FFT pass helpers (lds: float2[64*33], row-major [x][k]) -------
__device__ __forceinline__ void ifft_pass_x(const float2* __restrict__ F,
                                            float2* lds, const float* cs,
                                            const float* sn, int t) {
    __syncthreads();
    if (t < 33) {
        float ar[64], ai[64];
#pragma unroll
        for (int kx = 0; kx < 64; ++kx) {
            float2 v = F[kx * 33 + t];
            ar[kx] = v.x; ai[kx] = v.y;
        }
        fft64<1>(ar, ai, cs, sn);
#pragma unroll
        for (int x = 0; x < 64; ++x) lds[x * 33 + t] = make_float2(ar[x], ai[x]);
    }
    __syncthreads();
}

__device__ __forceinline__ void ifft_pass_y(const float2* lds, float* xr,
                                            float* xi, const float* cs,
                                            const float* sn, int t) {
#pragma unroll
    for (int k = 0; k <= 32; ++k) {
        float2 v = lds[t * 33 + k];
        xr[k] = v.x; xi[k] = v.y;
    }
#pragma unroll
    for (int k = 33; k < 64; ++k) {
        float2 v = lds[t * 33 + (64 - k)];
        xr[k] = v.x; xi[k] = -v.y;
    }
    fft64<1>(xr, xi, cs, sn);
}

__device__ __forceinline__ void fwd_pass_y(float* xr, float* xi, float2* lds,
                                           const float* cs, const float* sn,
                                           int t) {
    fft64<-1>(xr, xi, cs, sn);
#pragma unroll
    for (int k = 0; k <= 32; ++k) lds[t * 33 + k] = make_float2(xr[k], xi[k]);
}

__device__ __forceinline__ void fwd_pass_x(const float2* lds,
                                           float2* __restrict__ out,
                                           const float* cs, const float* sn,
                                           int t) {
    __syncthreads();
    if (t < 33) {
        float ar[64], ai[64];
#pragma unroll
        for (int x = 0; x < 64; ++x) {
            float2 v = lds[x * 33 + t];
            ar[x] = v.x; ai[x] = v.y;
        }
        fft64<-1>(ar, ai, cs, sn);
#pragma unroll
        for (int kx = 0; kx < 64; ++kx) out[kx * 33 + t] = make_float2(ar[kx], ai[kx]);
    }
}

// ---------------- h0 = x*Wi[c]+bi[c], then rfft2 -> Hf ---------------------
__global__ __launch_bounds__(64) void k_h0fft(const float* __restrict__ x,
                                              const float* __restrict__ Wi,
                                              const float* __restrict__ bi,
                                              float* __restrict__ h,
                                              float2* __restrict__ Hf) {
    __shared__ float cs[64], sn[64];
    __shared__ float2 lds[64 * 33];
    const int t = threadIdx.x;
    init_twiddles(cs, sn, t);
    __syncthreads();
    const int ib = blockIdx.x;        // b*64+c
    const int c = ib & 63, b = ib >> 6;
    const float wi = Wi[c], bc = bi[c];

    float xr[64], xi[64];
    const float4* xrow = (const float4*)(x + (size_t)b * IMGSZ + t * 64);
    float4* hrow = (float4*)(h + (size_t)ib * IMGSZ + t * 64);
#pragma unroll
    for (int k = 0; k < 16; ++k) {
        float4 v = xrow[k];
        v.x = v.x * wi + bc; v.y = v.y * wi + bc;
        v.z = v.z * wi + bc; v.w = v.w * wi + bc;
        hrow[k] = v;
        xr[4 * k + 0] = v.x; xr[4 * k + 1] = v.y;
        xr[4 * k + 2] = v.z; xr[4 * k + 3] = v.w;
    }
#pragma unroll
    for (int k = 0; k < 64; ++k) xi[k] = 0.0f;
    fwd_pass_y(xr, xi, lds, cs, sn, t);
    fwd_pass_x(lds, Hf + (size_t)ib * NFREQ, cs, sn, t);
}

// ---------------- irfft2(Rf) -> r; rh = sigmoid(r)*h; rfft2(rh) -> RHf -----
__global__ __launch_bounds__(64) void k_fifft_r(const float2* __restrict__ Rf,
                                                const float* __restrict__ h,
                                                float2* __restrict__ RHf) {
    __shared__ float cs[64], sn[64];
    __shared__ float2 lds[64 * 33];
    const int t = threadIdx.x;
    init_twiddles(cs, sn, t);
    const size_t ib = blockIdx.x;
    float xr[64], xi[64];

    ifft_pass_x(Rf + ib * NFREQ, lds, cs, sn, t);
    ifft_pass_y(lds, xr, xi, cs, sn, t);
    const float4* h4 = (const float4*)(h + ib * IMGSZ + t * 64);
#pragma unroll
    for (int k = 0; k < 16; ++k) {
        float4 hv = h4[k];
        xr[4 * k + 0] = sigmoidf_(xr[4 * k + 0] * INV_N) * hv.x;
        xr[4 * k + 1] = sigmoidf_(xr[4 * k + 1] * INV_N) * hv.y;
        xr[4 * k + 2] = sigmoidf_(xr[4 * k + 2] * INV_N) * hv.z;
        xr[4 * k + 3] = sigmoidf_(xr[4 * k + 3] * INV_N) * hv.w;
    }
#pragma unroll
    for (int k = 0; k < 64; ++k) xi[k] = 0.0f;
    fwd_pass_y(xr, xi, lds, cs, sn, t);
    fwd_pass_x(lds, RHf + ib * NFREQ, cs, sn, t);
}

// ---- irfft2(Zf)->z, irfft2(Nf)->n, h=(1-z)h+z*tanh(n); write h + rfft2(h) -
__global__ __launch_bounds__(64) void k_fifft_n(const float2* __restrict__ Nf,
                                                const float2* __restrict__ Zf,
                                                float* __restrict__ h,
                                                float2* __restrict__ Hfn) {
    __shared__ float cs[64], sn[64];
    __shared__ float2 lds[64 * 33];
    __shared__ float zbuf[64 * 64];
    const int t = threadIdx.x;
    init_twiddles(cs, sn, t);
    const size_t ib = blockIdx.x;
    float xr[64], xi[64];

    ifft_pass_x(Zf + ib * NFREQ, lds, cs, sn, t);
    ifft_pass_y(lds, xr, xi, cs, sn, t);
#pragma unroll
    for (int k = 0; k < 64; ++k) zbuf[t * 64 + k] = sigmoidf_(xr[k] * INV_N);

    ifft_pass_x(Nf + ib * NFREQ, lds, cs, sn, t);
    ifft_pass_y(lds, xr, xi, cs, sn, t);
    float4* h4 = (float4*)(h + ib * IMGSZ + t * 64);
    const float4* z4 = (const float4*)(zbuf + t * 64);
#pragma unroll
    for (int k = 0; k < 16; ++k) {
        float4 hv = h4[k];
        float4 zv = z4[k];
        hv.x = (1.0f - zv.x) * hv.x + zv.x * tanhf(xr[4 * k + 0] * INV_N);
        hv.y = (1.0f - zv.y) * hv.y + zv.y * tanhf(xr[4 * k + 1] * INV_N);
        hv.z = (1.0f - zv.z) * hv.z + zv.z * tanhf(xr[4 * k + 2] * INV_N);
        hv.w = (1.0f - zv.w) * hv.w + zv.w * tanhf(xr[4 * k + 3] * INV_N);
        h4[k] = hv;
        xr[4 * k + 0] = hv.x; xr[4 * k + 1] = hv.y;
        xr[4 * k + 2] = hv.z; xr[4 * k + 3] = hv.w;
    }
#pragma unroll
    for (int k = 0; k < 64; ++k) xi[k] = 0.0f;
    fwd_pass_y(xr, xi, lds, cs, sn, t);
    fwd_pass_x(lds, Hfn + ib * NFREQ, cs, sn, t);
}

// ---------------- pointwise complex channel mix ----------------------------
// O[b][o][f] = sum_i H[b][i][f] * w[i][o][f]   (complex)
// grid (66, 8, 2): x = 32-complex-freq tile, y = 8-o group, z = 8-b group.
// thread t: fq = t&7 (4 cf each), og = (t>>3)&7, wave w = t>>6 owns b-pair
// (b0 = z*8 + w*2). NBUF=2 LDS double-buffer, KI=4 i's per stage step
// (16 barriers; per-step compute ~1400 cyc covers ~900 cyc load latency):
//   Wl[buf][ki][arr][o*8+fq]  (float4)  -- pw2: wave w stages arr(tensor)=w,
//                                          ki 0..3 (4 gld each)
//   Hl[buf][ki][b_loc][slot]  (float4 = 2 cf), b_loc 0..7, slot = 2 cf --
//                               wave w stages ki=w, both b-halves (2 gld)
// global_load_lds writes wave-uniform base + lane*16; lane l = (o_l*8+fq_l)
// for weights, (b_loc*16 + slot) = ((l>>4)*16 + (l&15)) for Hf.
// All waves issue 6 gld/step (pw2) / 4 (pw1); __syncthreads drains vmcnt.
__device__ __forceinline__ void gld_lds16(const void* g, void* l) {
    __builtin_amdgcn_global_load_lds(
        (const __attribute__((address_space(1))) unsigned int*)g,
        (__attribute__((address_space(3))) unsigned int*)l, 16, 0, 0);
}

__device__ __forceinline__ void cmadd4(float (&are)[4], float (&aim)[4],
                                       const float4 hA, const float4 hB,
                                       const float4 wr, const float4 wi) {
    are[0] += hA.x * wr.x - hA.y * wi.x;  aim[0] += hA.x * wi.x + hA.y * wr.x;
    are[1] += hA.z * wr.y - hA.w * wi.y;  aim[1] += hA.z * wi.y + hA.w * wr.y;
    are[2] += hB.x * wr.z - hB.y * wi.z;  aim[2] += hB.x * wi.z + hB.y * wr.z;
    are[3] += hB.z * wr.w - hB.w * wi.w;  aim[3] += hB.z * wi.w + hB.w * wr.w;
}

__global__ __launch_bounds__(256, 4) void k_pw2(const float2* __restrict__ Hf,
                                                const float* __restrict__ wzr,
                                                const float* __restrict__ wzi,
                                                const float* __restrict__ wrr,
                                                const float* __restrict__ wri,
                                                float2* __restrict__ Zf,
                                                float2* __restrict__ Rf) {
    __shared__ float4 Wl[2][4][4][64];   // 32 KB
    __shared__ float4 Hl[2][4][8][16];   // 16 KB
    const int t  = threadIdx.x;
    const int l  = t & 63, w = t >> 6;       // lane, wave
    const int fq = t & 7,  og = (t >> 3) & 7;
    const int o  = blockIdx.y * 8 + og;
    const int b0 = blockIdx.z * 8 + w * 2;   // this wave's b-pair
    const int fA = blockIdx.x * 32 + fq * 4;
    const size_t wstep = (size_t)64 * NFREQ;

    // staging source bases (per-lane global addresses)
    const int o_l = l >> 3, fq_l = l & 7;
    const float* wa = (w == 0) ? wzr : (w == 1) ? wzi : (w == 2) ? wrr : wri;
    const float* wsrc = wa + (size_t)(blockIdx.y * 8 + o_l) * NFREQ
                           + blockIdx.x * 32 + fq_l * 4;
    // Hf staging: lane l covers b_loc = l>>4 (+4 for upper half), slot = l&15
    const float2* hsrcA = Hf + (size_t)((blockIdx.z * 8 + (l >> 4)) * 64) * NFREQ
                             + blockIdx.x * 32 + (l & 15) * 2;
    const float2* hsrcB = hsrcA + (size_t)4 * 64 * NFREQ;   // b_loc + 4

#define STAGE2(ii, bf) do {                                                    \
        const int _i0 = 4 * (ii);                                              \
        gld_lds16(wsrc + (size_t)(_i0 + 0) * wstep, &Wl[bf][0][w][0]);         \
        gld_lds16(wsrc + (size_t)(_i0 + 1) * wstep, &Wl[bf][1][w][0]);         \
        gld_lds16(wsrc + (size_t)(_i0 + 2) * wstep, &Wl[bf][2][w][0]);         \
        gld_lds16(wsrc + (size_t)(_i0 + 3) * wstep, &Wl[bf][3][w][0]);         \
        gld_lds16(hsrcA + (size_t)(_i0 + w) * NFREQ, &Hl[bf][w][0][0]);        \
        gld_lds16(hsrcB + (size_t)(_i0 + w) * NFREQ, &Hl[bf][w][4][0]);        \
    } while (0)

    float zre[2][4], zim[2][4], rre[2][4], rim[2][4];
#pragma unroll
    for (int b = 0; b < 2; ++b)
#pragma unroll
        for (int k = 0; k < 4; ++k) {
            zre[b][k] = 0.0f; zim[b][k] = 0.0f;
            rre[b][k] = 0.0f; rim[b][k] = 0.0f;
        }

    STAGE2(0, 0);
    __syncthreads();

    for (int s = 0; s < 16; ++s) {
        const int buf = s & 1;
        if (s < 15) STAGE2(s + 1, buf ^ 1);
#pragma unroll
        for (int ki = 0; ki < 4; ++ki) {
            const float4 vzr = Wl[buf][ki][0][og * 8 + fq];
            const float4 vzi = Wl[buf][ki][1][og * 8 + fq];
            const float4 vrr = Wl[buf][ki][2][og * 8 + fq];
            const float4 vri = Wl[buf][ki][3][og * 8 + fq];
#pragma unroll
            for (int bb = 0; bb < 2; ++bb) {
                const float4 hA = Hl[buf][ki][w * 2 + bb][2 * fq];
                const float4 hB = Hl[buf][ki][w * 2 + bb][2 * fq + 1];
                cmadd4(zre[bb], zim[bb], hA, hB, vzr, vzi);
                cmadd4(rre[bb], rim[bb], hA, hB, vrr, vri);
            }
        }
        __syncthreads();
    }
#undef STAGE2

#pragma unroll
    for (int b = 0; b < 2; ++b) {
        float4* pz = (float4*)(Zf + (size_t)((b0 + b) * 64 + o) * NFREQ + fA);
        float4* pr = (float4*)(Rf + (size_t)((b0 + b) * 64 + o) * NFREQ + fA);
        pz[0] = make_float4(zre[b][0], zim[b][0], zre[b][1], zim[b][1]);
        pz[1] = make_float4(zre[b][2], zim[b][2], zre[b][3], zim[b][3]);
        pr[0] = make_float4(rre[b][0], rim[b][0], rre[b][1], rim[b][1]);
        pr[1] = make_float4(rre[b][2], rim[b][2], rre[b][3], rim[b][3]);
    }
}

__global__ __launch_bounds__(256, 4) void k_pw1(const float2* __restrict__ Hf,
                                                const float* __restrict__ whr,
                                                const float* __restrict__ whi,
                                                float2* __restrict__ Of) {
    __shared__ float4 Wl[2][4][2][64];   // 16 KB
    __shared__ float4 Hl[2][4][8][16];   // 16 KB
    const int t  = threadIdx.x;
    const int l  = t & 63, w = t >> 6;
    const int fq = t & 7,  og = (t >> 3) & 7;
    const int o  = blockIdx.y * 8 + og;
    const int b0 = blockIdx.z * 8 + w * 2;
    const int fA = blockIdx.x * 32 + fq * 4;
    const size_t wstep = (size_t)64 * NFREQ;

    // wave w stages weight tensor (w&1), ki pair (w>>1)*2..+1 (2 gld)
    // and Hf ki=w, both halves (2 gld) -> 4 gld/wave uniform.
    const int o_l = l >> 3, fq_l = l & 7;
    const int kiA = (w >> 1) * 2, warr = w & 1;
    const float* wa = warr ? whi : whr;
    const float* wsrc = wa + (size_t)(blockIdx.y * 8 + o_l) * NFREQ
                           + blockIdx.x * 32 + fq_l * 4;
    const float2* hsrcA = Hf + (size_t)((blockIdx.z * 8 + (l >> 4)) * 64) * NFREQ
                             + blockIdx.x * 32 + (l & 15) * 2;
    const float2* hsrcB = hsrcA + (size_t)4 * 64 * NFREQ;

#define STAGE1(ii, bf) do {                                                    \
        const int _i0 = 4 * (ii);                                              \
        gld_lds16(wsrc + (size_t)(_i0 + kiA) * wstep,     &Wl[bf][kiA][warr][0]);     \
        gld_lds16(wsrc + (size_t)(_i0 + kiA + 1) * wstep, &Wl[bf][kiA + 1][warr][0]); \
        gld_lds16(hsrcA + (size_t)(_i0 + w) * NFREQ, &Hl[bf][w][0][0]);        \
        gld_lds16(hsrcB + (size_t)(_i0 + w) * NFREQ, &Hl[bf][w][4][0]);        \
    } while (0)

    float cre[2][4], cim[2][4];
#pragma unroll
    for (int b = 0; b < 2; ++b)
#pragma unroll
        for (int k = 0; k < 4; ++k) { cre[b][k] = 0.0f; cim[b][k] = 0.0f; }

    STAGE1(0, 0);
    __syncthreads();

    for (int s = 0; s < 16; ++s) {
        const int buf = s & 1;
        if (s < 15) STAGE1(s + 1, buf ^ 1);
#pragma unroll
        for (int ki = 0; ki < 4; ++ki) {
            const float4 vr = Wl[buf][ki][0][og * 8 + fq];
            const float4 vi = Wl[buf][ki][1][og * 8 + fq];
#pragma unroll
            for (int bb = 0; bb < 2; ++bb) {
                const float4 hA = Hl[buf][ki][w * 2 + bb][2 * fq];
                const float4 hB = Hl[buf][ki][w * 2 + bb][2 * fq + 1];
                cmadd4(cre[bb], cim[bb], hA, hB, vr, vi);
            }
        }
        __syncthreads();
    }
#undef STAGE1

#pragma unroll
    for (int b = 0; b < 2; ++b) {
        float4* po = (float4*)(Of + (size_t)((b0 + b) * 64 + o) * NFREQ + fA);
        po[0] = make_float4(cre[b][0], cim[b][0], cre[b][1], cim[b][1]);
        po[1] = make_float4(cre[b][2], cim[b][2], cre[b][3], cim[b][3]);
    }
}

// ---------------- y = h @ Wo + bo, per step --------------------------------
__global__ __launch_bounds__(256) void k_yproj(const float* __restrict__ h,
                                               const float* __restrict__ Wo,
                                               const float* __restrict__ bo,
                                               float* __restrict__ out,
                                               int step) {
    __shared__ float wo[64];
    const int t = threadIdx.x;
    if (t < 64) wo[t] = Wo[t];
    __syncthreads();
    const int b = blockIdx.x >> 4, xg = blockIdx.x & 15;
    const int xx = xg * 4 + (t >> 6), y = t & 63;
    const float* hp = h + (size_t)b * 64 * IMGSZ + xx * 64 + y;
    float acc = bo[0];
#pragma unroll 8
    for (int c = 0; c < 64; ++c) acc += hp[(size_t)c * IMGSZ] * wo[c];
    out[((size_t)b * 20 + step) * IMGSZ + xx * 64 + y] = acc;
}

// ---------------------------------------------------------------------------
extern "C" void kernel_launch(void* const* d_in, const int* in_sizes, int n_in,
                              void* d_out, int out_size, void* d_ws, size_t ws_size,
                              hipStream_t stream) {
    const float* x    = (const float*)d_in[0];
    // d_in[1] = num_time_steps (always 20 per setup_inputs)
    const float* Wi   = (const float*)d_in[2];
    const float* bi   = (const float*)d_in[3];
    const float* Wo   = (const float*)d_in[4];
    const float* bo   = (const float*)d_in[5];
    const float* Wz_r = (const float*)d_in[6];
    const float* Wz_i = (const float*)d_in[7];
    const float* Wr_r = (const float*)d_in[8];
    const float* Wr_i = (const float*)d_in[9];
    const float* Wh_r = (const float*)d_in[10];
    const float* Wh_i = (const float*)d_in[11];

    float* ws = (float*)d_ws;
    float* h = ws;                              // 4,194,304 floats
    float2* B0 = (float2*)(ws + 4194304);       // 2,162,688 float2 each
    float2* B1 = B0 + 2162688;
    float2* B2 = B1 + 2162688;
    float* outp = (float*)d_out;

    k_h0fft<<<NIMG, 64, 0, stream>>>(x, Wi, bi, h, B0);   // h0, Hf -> B0

    for (int t = 0; t < 20; ++t) {
        k_pw2<<<dim3(66, 8, 2), 256, 0, stream>>>(B0, Wz_r, Wz_i, Wr_r, Wr_i,
                                                  B1, B2);  // Zf->B1 Rf->B2
        k_fifft_r<<<NIMG, 64, 0, stream>>>(B2, h, B2);      // RHf -> B2
        k_pw1<<<dim3(66, 8, 2), 256, 0, stream>>>(B2, Wh_r, Wh_i, B0); // Nf->B0
        k_fifft_n<<<NIMG, 64, 0, stream>>>(B0, B1, h, B0);  // h, Hf_next -> B0
        k_yproj<<<256, 256, 0, stream>>>(h, Wo, bo, outp, t);
    }
}

// Round 6
// 4303.074 us; speedup vs baseline: 1.7107x; 1.0581x over previous
//
#include <hip/hip_runtime.h>
#include <math.h>

// ---------------------------------------------------------------------------
// FNO-GRU 2D: B=16, SX=SY=64, W=64 channels, T=20 steps, YH=33, NFREQ=2112.
// Weights stay in natural [i][o][f] layout (f fastest).
// Workspace (~69 MB):
//   h  : [b][c][x][y] float, 4,194,304
//   B0/B1/B2 : spectral float2 buffers, 2,162,688 each, image-major [img][f].
// Dispatches/step: pw2, fifft_r, pw1, fifft_n, yproj.
//
// LADDER: 195 (direct) -> 118 (gld_lds NBUF=2, r2) -> 7361 REGRESS (manual
// vmcnt, r3 -- DO NOT reintroduce) -> 110 (1b/wave 65% occ, r4 -- LDS-read
// floor doubled) -> 109 (KI=4, r5 -- neutral).
// Round-5 POST-MORTEM: pw2 pinned ~110 us across occupancy/KI knobs. Cause:
// global_load_lds forces hipcc to emit s_waitcnt vmcnt(0) before EVERY
// s_barrier (LDS-writing VMEM must drain) -> each of the staging round
// trips is exposed; depth/occupancy don't help 3 lockstep blocks/CU.
// Round-10 (this round): T14 reg-staging. global_load -> VGPR needs NO
// vmcnt drain at __syncthreads (no workgroup-visible side effect); the
// compiler's counted vmcnt lands before the ds_write that consumes the
// regs, one full iter (~900+ cyc) after issue -> latency hidden with zero
// inline asm. Geometry = round-2 verified shape (KI=2, same maps); new
// cost = 3 (pw2) / 2 (pw1) ds_write_b128 per wave-iter (+19% LDS pipe).
// Static reg sets A/B, loop unrolled by 2 (rule #20: no dynamic reg idx).
//
// NOTE (round-4 post-mortem, still applies): big per-thread arrays spill.
// Staging regs here are 6 float4 max, named, never runtime-indexed.
// ---------------------------------------------------------------------------

#define NIMG   1024         // B*W images
#define NFREQ  2112         // 64*33
#define IMGSZ  4096         // 64*64
#define INV_N  (1.0f/4096.0f)

constexpr int brev6(int i) {
    int r = 0;
    for (int b = 0; b < 6; ++b) r |= ((i >> b) & 1) << (5 - b);
    return r;
}

// 64-point complex FFT, fully unrolled radix-2 DIT. DSIGN=-1 fwd, +1 inv.
template <int DSIGN>
__device__ __forceinline__ void fft64(float* xr, float* xi,
                                      const float* cs, const float* sn) {
#pragma unroll
    for (int i = 0; i < 64; ++i) {
        const int j = brev6(i);
        if (j > i) {
            float tr = xr[i]; xr[i] = xr[j]; xr[j] = tr;
            float ti = xi[i]; xi[i] = xi[j]; xi[j] = ti;
        }
    }
#pragma unroll
    for (int s = 1; s <= 6; ++s) {
        const int m = 1 << s, h = m >> 1, step = 64 >> s;
#pragma unroll
        for (int j = 0; j < h; ++j) {
            const int tw = j * step;
            float c = 1.0f, sg = 0.0f;
            if (tw != 0) {
                c  = cs[tw];
                sg = (DSIGN < 0) ? -sn[tw] : sn[tw];
            }
#pragma unroll
            for (int k = j; k < 64; k += m) {
                const int p = k, q = k + h;
                const float vr = xr[q], vi = xi[q];
                float tr, ti;
                if (tw == 0) { tr = vr; ti = vi; }
                else         { tr = c * vr - sg * vi; ti = c * vi + sg * vr; }
                const float ur = xr[p], ui = xi[p];
                xr[p] = ur + tr; xi[p] = ui + ti;
                xr[q] = ur - tr; xi[q] = ui - ti;
            }
        }
    }
}

__device__ __forceinline__ void init_twiddles(float* cs, float* sn, int t) {
    float s, c;
    sincosf(6.28318530717958647692f * (float)t * (1.0f / 64.0f), &s, &c);
    cs[t] = c; sn[t] = s;
}

__device__ __forceinline__ float sigmoidf_(float v) {
    return 1.0f / (1.0f + expf(-v));
}

// ---- shared FFT pass helpers (lds: float2[64*33], row-major [x][k]) -------
__device__ __forceinline__ void ifft_pass_x(const float2* __restrict__ F,
                                            float2* lds, const float* cs,
                                            const float* sn, int t) {
    __syncthreads();
    if (t < 33) {
        float ar[64], ai[64];
#pragma unroll
        for (int kx = 0; kx < 64; ++kx) {
            float2 v = F[kx * 33 + t];
            ar[kx] = v.x; ai[kx] = v.y;
        }
        fft64<1>(ar, ai, cs, sn);
#pragma unroll
        for (int x = 0; x < 64; ++x) lds[x * 33 + t] = make_float2(ar[x], ai[x]);
    }
    __syncthreads();
}

__device__ __forceinline__ void ifft_pass_y(const float2* lds, float* xr,
                                            float* xi, const float* cs,
                                            const float* sn, int t) {
#pragma unroll
    for (int k = 0; k <= 32; ++k) {
        float2 v = lds[t * 33 + k];
        xr[k] = v.x; xi[k] = v.y;
    }
#pragma unroll
    for (int k = 33; k < 64; ++k) {
        float2 v = lds[t * 33 + (64 - k)];
        xr[k] = v.x; xi[k] = -v.y;
    }
    fft64<1>(xr, xi, cs, sn);
}

__device__ __forceinline__ void fwd_pass_y(float* xr, float* xi, float2* lds,
                                           const float* cs, const float* sn,
                                           int t) {
    fft64<-1>(xr, xi, cs, sn);
#pragma unroll
    for (int k = 0; k <= 32; ++k) lds[t * 33 + k] = make_float2(xr[k], xi[k]);
}

__device__ __forceinline__ void fwd_pass_x(const float2* lds,
                                           float2* __restrict__ out,
                                           const float* cs, const float* sn,
                                           int t) {
    __syncthreads();
    if (t < 33) {
        float ar[64], ai[64];
#pragma unroll
        for (int x = 0; x < 64; ++x) {
            float2 v = lds[x * 33 + t];
            ar[x] = v.x; ai[x] = v.y;
        }
        fft64<-1>(ar, ai, cs, sn);
#pragma unroll
        for (int kx = 0; kx < 64; ++kx) out[kx * 33 + t] = make_float2(ar[kx], ai[kx]);
    }
}

// ---------------- h0 = x*Wi[c]+bi[c], then rfft2 -> Hf ---------------------
__global__ __launch_bounds__(64) void k_h0fft(const float* __restrict__ x,
                                              const float* __restrict__ Wi,
                                              const float* __restrict__ bi,
                                              float* __restrict__ h,
                                              float2* __restrict__ Hf) {
    __shared__ float cs[64], sn[64];
    __shared__ float2 lds[64 * 33];
    const int t = threadIdx.x;
    init_twiddles(cs, sn, t);
    __syncthreads();
    const int ib = blockIdx.x;        // b*64+c
    const int c = ib & 63, b = ib >> 6;
    const float wi = Wi[c], bc = bi[c];

    float xr[64], xi[64];
    const float4* xrow = (const float4*)(x + (size_t)b * IMGSZ + t * 64);
    float4* hrow = (float4*)(h + (size_t)ib * IMGSZ + t * 64);
#pragma unroll
    for (int k = 0; k < 16; ++k) {
        float4 v = xrow[k];
        v.x = v.x * wi + bc; v.y = v.y * wi + bc;
        v.z = v.z * wi + bc; v.w = v.w * wi + bc;
        hrow[k] = v;
        xr[4 * k + 0] = v.x; xr[4 * k + 1] = v.y;
        xr[4 * k + 2] = v.z; xr[4 * k + 3] = v.w;
    }
#pragma unroll
    for (int k = 0; k < 64; ++k) xi[k] = 0.0f;
    fwd_pass_y(xr, xi, lds, cs, sn, t);
    fwd_pass_x(lds, Hf + (size_t)ib * NFREQ, cs, sn, t);
}

// ---------------- irfft2(Rf) -> r; rh = sigmoid(r)*h; rfft2(rh) -> RHf -----
__global__ __launch_bounds__(64) void k_fifft_r(const float2* __restrict__ Rf,
                                                const float* __restrict__ h,
                                                float2* __restrict__ RHf) {
    __shared__ float cs[64], sn[64];
    __shared__ float2 lds[64 * 33];
    const int t = threadIdx.x;
    init_twiddles(cs, sn, t);
    const size_t ib = blockIdx.x;
    float xr[64], xi[64];

    ifft_pass_x(Rf + ib * NFREQ, lds, cs, sn, t);
    ifft_pass_y(lds, xr, xi, cs, sn, t);
    const float4* h4 = (const float4*)(h + ib * IMGSZ + t * 64);
#pragma unroll
    for (int k = 0; k < 16; ++k) {
        float4 hv = h4[k];
        xr[4 * k + 0] = sigmoidf_(xr[4 * k + 0] * INV_N) * hv.x;
        xr[4 * k + 1] = sigmoidf_(xr[4 * k + 1] * INV_N) * hv.y;
        xr[4 * k + 2] = sigmoidf_(xr[4 * k + 2] * INV_N) * hv.z;
        xr[4 * k + 3] = sigmoidf_(xr[4 * k + 3] * INV_N) * hv.w;
    }
#pragma unroll
    for (int k = 0; k < 64; ++k) xi[k] = 0.0f;
    fwd_pass_y(xr, xi, lds, cs, sn, t);
    fwd_pass_x(lds, RHf + ib * NFREQ, cs, sn, t);
}

// ---- irfft2(Zf)->z, irfft2(Nf)->n, h=(1-z)h+z*tanh(n); write h + rfft2(h) -
__global__ __launch_bounds__(64) void k_fifft_n(const float2* __restrict__ Nf,
                                                const float2* __restrict__ Zf,
                                                float* __restrict__ h,
                                                float2* __restrict__ Hfn) {
    __shared__ float cs[64], sn[64];
    __shared__ float2 lds[64 * 33];
    __shared__ float zbuf[64 * 64];
    const int t = threadIdx.x;
    init_twiddles(cs, sn, t);
    const size_t ib = blockIdx.x;
    float xr[64], xi[64];

    ifft_pass_x(Zf + ib * NFREQ, lds, cs, sn, t);
    ifft_pass_y(lds, xr, xi, cs, sn, t);
#pragma unroll
    for (int k = 0; k < 64; ++k) zbuf[t * 64 + k] = sigmoidf_(xr[k] * INV_N);

    ifft_pass_x(Nf + ib * NFREQ, lds, cs, sn, t);
    ifft_pass_y(lds, xr, xi, cs, sn, t);
    float4* h4 = (float4*)(h + ib * IMGSZ + t * 64);
    const float4* z4 = (const float4*)(zbuf + t * 64);
#pragma unroll
    for (int k = 0; k < 16; ++k) {
        float4 hv = h4[k];
        float4 zv = z4[k];
        hv.x = (1.0f - zv.x) * hv.x + zv.x * tanhf(xr[4 * k + 0] * INV_N);
        hv.y = (1.0f - zv.y) * hv.y + zv.y * tanhf(xr[4 * k + 1] * INV_N);
        hv.z = (1.0f - zv.z) * hv.z + zv.z * tanhf(xr[4 * k + 2] * INV_N);
        hv.w = (1.0f - zv.w) * hv.w + zv.w * tanhf(xr[4 * k + 3] * INV_N);
        h4[k] = hv;
        xr[4 * k + 0] = hv.x; xr[4 * k + 1] = hv.y;
        xr[4 * k + 2] = hv.z; xr[4 * k + 3] = hv.w;
    }
#pragma unroll
    for (int k = 0; k < 64; ++k) xi[k] = 0.0f;
    fwd_pass_y(xr, xi, lds, cs, sn, t);
    fwd_pass_x(lds, Hfn + ib * NFREQ, cs, sn, t);
}

// ---------------- pointwise complex channel mix ----------------------------
// O[b][o][f] = sum_i H[b][i][f] * w[i][o][f]   (complex)
// grid (66, 8, 2): x = 32-complex-freq tile, y = 8-o group, z = 8-b group.
// thread t: fq = t&7 (4 cf each), og = (t>>3)&7, wave w = t>>6 owns b-pair.
// T14 reg-staged double buffer, KI=2 per batch (batches 0..31):
//   lane loads its 16B from global -> named reg set (A/B alternate) ->
//   ds_write into LDS next iter. LDS layouts = round-2 verified maps:
//   Wl[buf][ki][arr][o*8+fq] (float4), lane l writes [arr=w][l].
//   Hl[buf][ki][b_loc][slot], lane l writes (w&1)*64 + l  (b_loc=(w&1)*4
//   + l>>4, slot=l&15); wave w stages ki = w>>1.
// Per iter s: ds_write batch s+1 -> LDS[buf^1]; issue loads batch s+2;
// compute LDS[buf]; __syncthreads. Loads-to-reg cross barriers freely
// (no vmcnt drain needed); compiler's counted vmcnt sits at the ds_write.
__device__ __forceinline__ void cmadd4(float (&are)[4], float (&aim)[4],
                                       const float4 hA, const float4 hB,
                                       const float4 wr, const float4 wi) {
    are[0] += hA.x * wr.x - hA.y * wi.x;  aim[0] += hA.x * wi.x + hA.y * wr.x;
    are[1] += hA.z * wr.y - hA.w * wi.y;  aim[1] += hA.z * wi.y + hA.w * wr.y;
    are[2] += hB.x * wr.z - hB.y * wi.z;  aim[2] += hB.x * wi.z + hB.y * wr.z;
    are[3] += hB.z * wr.w - hB.w * wi.w;  aim[3] += hB.z * wi.w + hB.w * wr.w;
}

__global__ __launch_bounds__(256) void k_pw2(const float2* __restrict__ Hf,
                                             const float* __restrict__ wzr,
                                             const float* __restrict__ wzi,
                                             const float* __restrict__ wrr,
                                             const float* __restrict__ wri,
                                             float2* __restrict__ Zf,
                                             float2* __restrict__ Rf) {
    __shared__ float4 Wl[2][2][4][64];   // 16 KB
    __shared__ float4 Hl[2][2][8][16];   //  8 KB
    const int t  = threadIdx.x;
    const int l  = t & 63, w = t >> 6;       // lane, wave
    const int fq = t & 7,  og = (t >> 3) & 7;
    const int o  = blockIdx.y * 8 + og;
    const int b0 = blockIdx.z * 8 + w * 2;
    const int fA = blockIdx.x * 32 + fq * 4;
    const size_t wstep = (size_t)64 * NFREQ;

    // staging source bases (per-lane global addresses, round-2 maps)
    const int o_l = l >> 3, fq_l = l & 7;
    const float* wa = (w == 0) ? wzr : (w == 1) ? wzi : (w == 2) ? wrr : wri;
    const float* wsrc = wa + (size_t)(blockIdx.y * 8 + o_l) * NFREQ
                           + blockIdx.x * 32 + fq_l * 4;
    const int ski = w >> 1;                   // Hf ki staged by this wave
    const int sb  = (w & 1) * 4 + (l >> 4);   // local b staged by this lane
    const float2* hsrc = Hf + (size_t)((blockIdx.z * 8 + sb) * 64) * NFREQ
                            + blockIdx.x * 32 + (l & 15) * 2;

    float4 aw0, aw1, ah;   // reg set A
    float4 bw0, bw1, bh;   // reg set B

#define LOADB(ii, r0, r1, rh_) do {                                            \
        r0  = *(const float4*)(wsrc + (size_t)(2 * (ii)) * wstep);             \
        r1  = *(const float4*)(wsrc + (size_t)(2 * (ii) + 1) * wstep);         \
        rh_ = *(const float4*)(hsrc + (size_t)(2 * (ii) + ski) * NFREQ);       \
    } while (0)
#define WRITEB(bf, r0, r1, rh_) do {                                           \
        Wl[bf][0][w][l] = r0;                                                  \
        Wl[bf][1][w][l] = r1;                                                  \
        (&Hl[bf][ski][0][0])[(w & 1) * 64 + l] = rh_;                          \
    } while (0)
#define COMP(bf) do {                                                          \
        _Pragma("unroll")                                                      \
        for (int ki = 0; ki < 2; ++ki) {                                       \
            const float4 vzr = Wl[bf][ki][0][og * 8 + fq];                     \
            const float4 vzi = Wl[bf][ki][1][og * 8 + fq];                     \
            const float4 vrr = Wl[bf][ki][2][og * 8 + fq];                     \
            const float4 vri = Wl[bf][ki][3][og * 8 + fq];                     \
            _Pragma("unroll")                                                  \
            for (int bb = 0; bb < 2; ++bb) {                                   \
                const float4 hA = Hl[bf][ki][w * 2 + bb][2 * fq];              \
                const float4 hB = Hl[bf][ki][w * 2 + bb][2 * fq + 1];          \
                cmadd4(zre[bb], zim[bb], hA, hB, vzr, vzi);                    \
                cmadd4(rre[bb], rim[bb], hA, hB, vrr, vri);                    \
            }                                                                  \
        }                                                                      \
    } while (0)

    float zre[2][4], zim[2][4], rre[2][4], rim[2][4];
#pragma unroll
    for (int b = 0; b < 2; ++b)
#pragma unroll
        for (int k = 0; k < 4; ++k) {
            zre[b][k] = 0.0f; zim[b][k] = 0.0f;
            rre[b][k] = 0.0f; rim[b][k] = 0.0f;
        }

    // prologue: batch 0 -> regs -> LDS[0]; batch 1 -> regs (in flight)
    LOADB(0, aw0, aw1, ah);
    WRITEB(0, aw0, aw1, ah);
    LOADB(1, bw0, bw1, bh);
    __syncthreads();

    for (int s = 0; s < 32; s += 2) {
        // iter s (even): B holds batch s+1 -> LDS[1]; load batch s+2 -> A
        WRITEB(1, bw0, bw1, bh);
        if (s < 30) LOADB(s + 2, aw0, aw1, ah);
        COMP(0);
        __syncthreads();
        // iter s+1 (odd): A holds batch s+2 -> LDS[0]; load batch s+3 -> B
        if (s < 30) WRITEB(0, aw0, aw1, ah);
        if (s < 28) LOADB(s + 3, bw0, bw1, bh);
        COMP(1);
        __syncthreads();
    }
#undef LOADB
#undef WRITEB
#undef COMP

#pragma unroll
    for (int b = 0; b < 2; ++b) {
        float4* pz = (float4*)(Zf + (size_t)((b0 + b) * 64 + o) * NFREQ + fA);
        float4* pr = (float4*)(Rf + (size_t)((b0 + b) * 64 + o) * NFREQ + fA);
        pz[0] = make_float4(zre[b][0], zim[b][0], zre[b][1], zim[b][1]);
        pz[1] = make_float4(zre[b][2], zim[b][2], zre[b][3], zim[b][3]);
        pr[0] = make_float4(rre[b][0], rim[b][0], rre[b][1], rim[b][1]);
        pr[1] = make_float4(rre[b][2], rim[b][2], rre[b][3], rim[b][3]);
    }
}

__global__ __launch_bounds__(256) void k_pw1(const float2* __restrict__ Hf,
                                             const float* __restrict__ whr,
                                             const float* __restrict__ whi,
                                             float2* __restrict__ Of) {
    __shared__ float4 Wl[2][2][2][64];   // 8 KB
    __shared__ float4 Hl[2][2][8][16];   // 8 KB
    const int t  = threadIdx.x;
    const int l  = t & 63, w = t >> 6;
    const int fq = t & 7,  og = (t >> 3) & 7;
    const int o  = blockIdx.y * 8 + og;
    const int b0 = blockIdx.z * 8 + w * 2;
    const int fA = blockIdx.x * 32 + fq * 4;
    const size_t wstep = (size_t)64 * NFREQ;

    // wave w stages weight (ki=w>>1, arr=w&1) and Hf (ki=w>>1, half=w&1)
    const int o_l = l >> 3, fq_l = l & 7;
    const int ski = w >> 1, warr = w & 1;
    const float* wa = warr ? whi : whr;
    const float* wsrc = wa + (size_t)(blockIdx.y * 8 + o_l) * NFREQ
                           + blockIdx.x * 32 + fq_l * 4;
    const int sb  = (w & 1) * 4 + (l >> 4);
    const float2* hsrc = Hf + (size_t)((blockIdx.z * 8 + sb) * 64) * NFREQ
                            + blockIdx.x * 32 + (l & 15) * 2;

    float4 aw, ah;   // reg set A
    float4 bw, bh;   // reg set B

#define LOADB(ii, r0, rh_) do {                                                \
        r0  = *(const float4*)(wsrc + (size_t)(2 * (ii) + ski) * wstep);       \
        rh_ = *(const float4*)(hsrc + (size_t)(2 * (ii) + ski) * NFREQ);       \
    } while (0)
#define WRITEB(bf, r0, rh_) do {                                               \
        Wl[bf][ski][warr][l] = r0;                                             \
        (&Hl[bf][ski][0][0])[(w & 1) * 64 + l] = rh_;                          \
    } while (0)
#define COMP(bf) do {                                                          \
        _Pragma("unroll")                                                      \
        for (int ki = 0; ki < 2; ++ki) {                                       \
            const float4 vr = Wl[bf][ki][0][og * 8 + fq];                      \
            const float4 vi = Wl[bf][ki][1][og * 8 + fq];                      \
            _Pragma("unroll")                                                  \
            for (int bb = 0; bb < 2; ++bb) {                                   \
                const float4 hA = Hl[bf][ki][w * 2 + bb][2 * fq];              \
                const float4 hB = Hl[bf][ki][w * 2 + bb][2 * fq + 1];          \
                cmadd4(cre[bb], cim[bb], hA, hB, vr, vi);                      \
            }                                                                  \
        }                                                                      \
    } while (0)

    float cre[2][4], cim[2][4];
#pragma unroll
    for (int b = 0; b < 2; ++b)
#pragma unroll
        for (int k = 0; k < 4; ++k) { cre[b][k] = 0.0f; cim[b][k] = 0.0f; }

    LOADB(0, aw, ah);
    WRITEB(0, aw, ah);
    LOADB(1, bw, bh);
    __syncthreads();

    for (int s = 0; s < 32; s += 2) {
        WRITEB(1, bw, bh);
        if (s < 30) LOADB(s + 2, aw, ah);
        COMP(0);
        __syncthreads();
        if (s < 30) WRITEB(0, aw, ah);
        if (s < 28) LOADB(s + 3, bw, bh);
        COMP(1);
        __syncthreads();
    }
#undef LOADB
#undef WRITEB
#undef COMP

#pragma unroll
    for (int b = 0; b < 2; ++b) {
        float4* po = (float4*)(Of + (size_t)((b0 + b) * 64 + o) * NFREQ + fA);
        po[0] = make_float4(cre[b][0], cim[b][0], cre[b][1], cim[b][1]);
        po[1] = make_float4(cre[b][2], cim[b][2], cre[b][3], cim[b][3]);
    }
}

// ---------------- y = h @ Wo + bo, per step --------------------------------
__global__ __launch_bounds__(256) void k_yproj(const float* __restrict__ h,
                                               const float* __restrict__ Wo,
                                               const float* __restrict__ bo,
                                               float* __restrict__ out,
                                               int step) {
    __shared__ float wo[64];
    const int t = threadIdx.x;
    if (t < 64) wo[t] = Wo[t];
    __syncthreads();
    const int b = blockIdx.x >> 4, xg = blockIdx.x & 15;
    const int xx = xg * 4 + (t >> 6), y = t & 63;
    const float* hp = h + (size_t)b * 64 * IMGSZ + xx * 64 + y;
    float acc = bo[0];
#pragma unroll 8
    for (int c = 0; c < 64; ++c) acc += hp[(size_t)c * IMGSZ] * wo[c];
    out[((size_t)b * 20 + step) * IMGSZ + xx * 64 + y] = acc;
}

// ---------------------------------------------------------------------------
extern "C" void kernel_launch(void* const* d_in, const int* in_sizes, int n_in,
                              void* d_out, int out_size, void* d_ws, size_t ws_size,
                              hipStream_t stream) {
    const float* x    = (const float*)d_in[0];
    // d_in[1] = num_time_steps (always 20 per setup_inputs)
    const float* Wi   = (const float*)d_in[2];
    const float* bi   = (const float*)d_in[3];
    const float* Wo   = (const float*)d_in[4];
    const float* bo   = (const float*)d_in[5];
    const float* Wz_r = (const float*)d_in[6];
    const float* Wz_i = (const float*)d_in[7];
    const float* Wr_r = (const float*)d_in[8];
    const float* Wr_i = (const float*)d_in[9];
    const float* Wh_r = (const float*)d_in[10];
    const float* Wh_i = (const float*)d_in[11];

    float* ws = (float*)d_ws;
    float* h = ws;                              // 4,194,304 floats
    float2* B0 = (float2*)(ws + 4194304);       // 2,162,688 float2 each
    float2* B1 = B0 + 2162688;
    float2* B2 = B1 + 2162688;
    float* outp = (float*)d_out;

    k_h0fft<<<NIMG, 64, 0, stream>>>(x, Wi, bi, h, B0);   // h0, Hf -> B0

    for (int t = 0; t < 20; ++t) {
        k_pw2<<<dim3(66, 8, 2), 256, 0, stream>>>(B0, Wz_r, Wz_i, Wr_r, Wr_i,
                                                  B1, B2);  // Zf->B1 Rf->B2
        k_fifft_r<<<NIMG, 64, 0, stream>>>(B2, h, B2);      // RHf -> B2
        k_pw1<<<dim3(66, 8, 2), 256, 0, stream>>>(B2, Wh_r, Wh_i, B0); // Nf->B0
        k_fifft_n<<<NIMG, 64, 0, stream>>>(B0, B1, h, B0);  // h, Hf_next -> B0
        k_yproj<<<256, 256, 0, stream>>>(h, Wo, bo, outp, t);
    }
}

// Round 8
// 4226.138 us; speedup vs baseline: 1.7418x; 1.0182x over previous
//
#include <hip/hip_runtime.h>
#include <math.h>

// ---------------------------------------------------------------------------
// FNO-GRU 2D: B=16, SX=SY=64, W=64 channels, T=20 steps, YH=33, NFREQ=2112.
// Weights stay in natural [i][o][f] layout (f fastest).
// Workspace (~69 MB):
//   h  : [b][c][x][y] float, 4,194,304
//   B0/B1/B2 : spectral float2 buffers, 2,162,688 each, image-major [img][f].
// Dispatches/step: pw2, fifft_r, pw1, fifft_n, yproj.
//
// LADDER: 195 (direct) -> 118 (gld_lds NBUF=2) -> 7361 REGRESS (manual
// vmcnt r3 -- DO NOT reintroduce) -> 110 (1b/wave) -> 109 (KI=4) ->
// 93 (T14 reg-staging, r6) -> r7 infra flake (container died pre-compile;
// audit of dist-2 schedule/staging/guards clean -> resubmit unchanged).
// Round-6 changes under test:
//  1. pw2/pw1: reg prefetch distance 1 -> 2 batches (load b+3 while
//     ds_writing b+1; still 2 reg sets, same verified sync structure).
//     Adds ~700 wave-cycles of load->consume slack to cover L3/HBM.
//  2. fifft_n: zbuf[64][64] was a 64-way bank conflict (1.93M/dispatch,
//     every lane hits bank k&31). Pad to [64*65] + scalar access.
//  3. FFT x-passes: F[kx*33+t] direct loads/stores are 64 scattered
//     33-lane 8B ops. Stage image through LDS with coalesced float4
//     copies (single-wave blocks -> lockstep-safe read-then-write).
// ---------------------------------------------------------------------------

#define NIMG   1024         // B*W images
#define NFREQ  2112         // 64*33
#define IMGSZ  4096         // 64*64
#define INV_N  (1.0f/4096.0f)

constexpr int brev6(int i) {
    int r = 0;
    for (int b = 0; b < 6; ++b) r |= ((i >> b) & 1) << (5 - b);
    return r;
}

// 64-point complex FFT, fully unrolled radix-2 DIT. DSIGN=-1 fwd, +1 inv.
template <int DSIGN>
__device__ __forceinline__ void fft64(float* xr, float* xi,
                                      const float* cs, const float* sn) {
#pragma unroll
    for (int i = 0; i < 64; ++i) {
        const int j = brev6(i);
        if (j > i) {
            float tr = xr[i]; xr[i] = xr[j]; xr[j] = tr;
            float ti = xi[i]; xi[i] = xi[j]; xi[j] = ti;
        }
    }
#pragma unroll
    for (int s = 1; s <= 6; ++s) {
        const int m = 1 << s, h = m >> 1, step = 64 >> s;
#pragma unroll
        for (int j = 0; j < h; ++j) {
            const int tw = j * step;
            float c = 1.0f, sg = 0.0f;
            if (tw != 0) {
                c  = cs[tw];
                sg = (DSIGN < 0) ? -sn[tw] : sn[tw];
            }
#pragma unroll
            for (int k = j; k < 64; k += m) {
                const int p = k, q = k + h;
                const float vr = xr[q], vi = xi[q];
                float tr, ti;
                if (tw == 0) { tr = vr; ti = vi; }
                else         { tr = c * vr - sg * vi; ti = c * vi + sg * vr; }
                const float ur = xr[p], ui = xi[p];
                xr[p] = ur + tr; xi[p] = ui + ti;
                xr[q] = ur - tr; xi[q] = ui - ti;
            }
        }
    }
}

__device__ __forceinline__ void init_twiddles(float* cs, float* sn, int t) {
    float s, c;
    sincosf(6.28318530717958647692f * (float)t * (1.0f / 64.0f), &s, &c);
    cs[t] = c; sn[t] = s;
}

__device__ __forceinline__ float sigmoidf_(float v) {
    return 1.0f / (1.0f + expf(-v));
}

// ---- shared FFT pass helpers (lds: float2[64*33], row-major [x][k]) -------
// lds must be 16B-aligned (declared as float4[1056] in kernels).

// coalesced image copy helpers (64 threads, 1056 float4s)
__device__ __forceinline__ void copy_g2l(float4* dst, const float4* src, int t) {
#pragma unroll
    for (int j = 0; j < 16; ++j) dst[j * 64 + t] = src[j * 64 + t];
    if (t < 32) dst[1024 + t] = src[1024 + t];
}
__device__ __forceinline__ void copy_l2g(float4* dst, const float4* src, int t) {
#pragma unroll
    for (int j = 0; j < 16; ++j) dst[j * 64 + t] = src[j * 64 + t];
    if (t < 32) dst[1024 + t] = src[1024 + t];
}

// inverse fft along x: stage F into lds (coalesced), then column FFTs
// in-place (lockstep read-then-write within the single wave).
__device__ __forceinline__ void ifft_pass_x(const float2* __restrict__ F,
                                            float2* lds, const float* cs,
                                            const float* sn, int t) {
    __syncthreads();
    copy_g2l((float4*)lds, (const float4*)F, t);
    __syncthreads();
    if (t < 33) {
        float ar[64], ai[64];
#pragma unroll
        for (int kx = 0; kx < 64; ++kx) {
            float2 v = lds[kx * 33 + t];
            ar[kx] = v.x; ai[kx] = v.y;
        }
        fft64<1>(ar, ai, cs, sn);
#pragma unroll
        for (int x = 0; x < 64; ++x) lds[x * 33 + t] = make_float2(ar[x], ai[x]);
    }
    __syncthreads();
}

__device__ __forceinline__ void ifft_pass_y(const float2* lds, float* xr,
                                            float* xi, const float* cs,
                                            const float* sn, int t) {
#pragma unroll
    for (int k = 0; k <= 32; ++k) {
        float2 v = lds[t * 33 + k];
        xr[k] = v.x; xi[k] = v.y;
    }
#pragma unroll
    for (int k = 33; k < 64; ++k) {
        float2 v = lds[t * 33 + (64 - k)];
        xr[k] = v.x; xi[k] = -v.y;
    }
    fft64<1>(xr, xi, cs, sn);
}

__device__ __forceinline__ void fwd_pass_y(float* xr, float* xi, float2* lds,
                                           const float* cs, const float* sn,
                                           int t) {
    fft64<-1>(xr, xi, cs, sn);
#pragma unroll
    for (int k = 0; k <= 32; ++k) lds[t * 33 + k] = make_float2(xr[k], xi[k]);
}

// forward fft along x of lds columns, results back into lds, then
// coalesced copy to global.
__device__ __forceinline__ void fwd_pass_x(float2* lds,
                                           float2* __restrict__ out,
                                           const float* cs, const float* sn,
                                           int t) {
    __syncthreads();
    if (t < 33) {
        float ar[64], ai[64];
#pragma unroll
        for (int x = 0; x < 64; ++x) {
            float2 v = lds[x * 33 + t];
            ar[x] = v.x; ai[x] = v.y;
        }
        fft64<-1>(ar, ai, cs, sn);
#pragma unroll
        for (int kx = 0; kx < 64; ++kx) lds[kx * 33 + t] = make_float2(ar[kx], ai[kx]);
    }
    __syncthreads();
    copy_l2g((float4*)out, (const float4*)lds, t);
}

// ---------------- h0 = x*Wi[c]+bi[c], then rfft2 -> Hf ---------------------
__global__ __launch_bounds__(64) void k_h0fft(const float* __restrict__ x,
                                              const float* __restrict__ Wi,
                                              const float* __restrict__ bi,
                                              float* __restrict__ h,
                                              float2* __restrict__ Hf) {
    __shared__ float cs[64], sn[64];
    __shared__ float4 lds4[1056];
    float2* lds = (float2*)lds4;
    const int t = threadIdx.x;
    init_twiddles(cs, sn, t);
    __syncthreads();
    const int ib = blockIdx.x;        // b*64+c
    const int c = ib & 63, b = ib >> 6;
    const float wi = Wi[c], bc = bi[c];

    float xr[64], xi[64];
    const float4* xrow = (const float4*)(x + (size_t)b * IMGSZ + t * 64);
    float4* hrow = (float4*)(h + (size_t)ib * IMGSZ + t * 64);
#pragma unroll
    for (int k = 0; k < 16; ++k) {
        float4 v = xrow[k];
        v.x = v.x * wi + bc; v.y = v.y * wi + bc;
        v.z = v.z * wi + bc; v.w = v.w * wi + bc;
        hrow[k] = v;
        xr[4 * k + 0] = v.x; xr[4 * k + 1] = v.y;
        xr[4 * k + 2] = v.z; xr[4 * k + 3] = v.w;
    }
#pragma unroll
    for (int k = 0; k < 64; ++k) xi[k] = 0.0f;
    fwd_pass_y(xr, xi, lds, cs, sn, t);
    fwd_pass_x(lds, Hf + (size_t)ib * NFREQ, cs, sn, t);
}

// ---------------- irfft2(Rf) -> r; rh = sigmoid(r)*h; rfft2(rh) -> RHf -----
__global__ __launch_bounds__(64) void k_fifft_r(const float2* __restrict__ Rf,
                                                const float* __restrict__ h,
                                                float2* __restrict__ RHf) {
    __shared__ float cs[64], sn[64];
    __shared__ float4 lds4[1056];
    float2* lds = (float2*)lds4;
    const int t = threadIdx.x;
    init_twiddles(cs, sn, t);
    const size_t ib = blockIdx.x;
    float xr[64], xi[64];

    ifft_pass_x(Rf + ib * NFREQ, lds, cs, sn, t);
    ifft_pass_y(lds, xr, xi, cs, sn, t);
    const float4* h4 = (const float4*)(h + ib * IMGSZ + t * 64);
#pragma unroll
    for (int k = 0; k < 16; ++k) {
        float4 hv = h4[k];
        xr[4 * k + 0] = sigmoidf_(xr[4 * k + 0] * INV_N) * hv.x;
        xr[4 * k + 1] = sigmoidf_(xr[4 * k + 1] * INV_N) * hv.y;
        xr[4 * k + 2] = sigmoidf_(xr[4 * k + 2] * INV_N) * hv.z;
        xr[4 * k + 3] = sigmoidf_(xr[4 * k + 3] * INV_N) * hv.w;
    }
#pragma unroll
    for (int k = 0; k < 64; ++k) xi[k] = 0.0f;
    fwd_pass_y(xr, xi, lds, cs, sn, t);
    fwd_pass_x(lds, RHf + ib * NFREQ, cs, sn, t);
}

// ---- irfft2(Zf)->z, irfft2(Nf)->n, h=(1-z)h+z*tanh(n); write h + rfft2(h) -
__global__ __launch_bounds__(64) void k_fifft_n(const float2* __restrict__ Nf,
                                                const float2* __restrict__ Zf,
                                                float* __restrict__ h,
                                                float2* __restrict__ Hfn) {
    __shared__ float cs[64], sn[64];
    __shared__ float4 lds4[1056];
    __shared__ float zbuf[64 * 65];   // padded: bank = (t+k)&31, conflict-free
    float2* lds = (float2*)lds4;
    const int t = threadIdx.x;
    init_twiddles(cs, sn, t);
    const size_t ib = blockIdx.x;
    float xr[64], xi[64];

    ifft_pass_x(Zf + ib * NFREQ, lds, cs, sn, t);
    ifft_pass_y(lds, xr, xi, cs, sn, t);
#pragma unroll
    for (int k = 0; k < 64; ++k) zbuf[t * 65 + k] = sigmoidf_(xr[k] * INV_N);

    ifft_pass_x(Nf + ib * NFREQ, lds, cs, sn, t);
    ifft_pass_y(lds, xr, xi, cs, sn, t);
    float4* h4 = (float4*)(h + ib * IMGSZ + t * 64);
    const float* zrow = zbuf + t * 65;
#pragma unroll
    for (int k = 0; k < 16; ++k) {
        float4 hv = h4[k];
        const float z0 = zrow[4 * k + 0], z1 = zrow[4 * k + 1];
        const float z2 = zrow[4 * k + 2], z3 = zrow[4 * k + 3];
        hv.x = (1.0f - z0) * hv.x + z0 * tanhf(xr[4 * k + 0] * INV_N);
        hv.y = (1.0f - z1) * hv.y + z1 * tanhf(xr[4 * k + 1] * INV_N);
        hv.z = (1.0f - z2) * hv.z + z2 * tanhf(xr[4 * k + 2] * INV_N);
        hv.w = (1.0f - z3) * hv.w + z3 * tanhf(xr[4 * k + 3] * INV_N);
        h4[k] = hv;
        xr[4 * k + 0] = hv.x; xr[4 * k + 1] = hv.y;
        xr[4 * k + 2] = hv.z; xr[4 * k + 3] = hv.w;
    }
#pragma unroll
    for (int k = 0; k < 64; ++k) xi[k] = 0.0f;
    fwd_pass_y(xr, xi, lds, cs, sn, t);
    fwd_pass_x(lds, Hfn + ib * NFREQ, cs, sn, t);
}

// ---------------- pointwise complex channel mix ----------------------------
// O[b][o][f] = sum_i H[b][i][f] * w[i][o][f]   (complex)
// grid (66, 8, 2): x = 32-complex-freq tile, y = 8-o group, z = 8-b group.
// thread t: fq = t&7 (4 cf each), og = (t>>3)&7, wave w = t>>6 owns b-pair.
// T14 reg-staged double buffer, KI=2 per batch, prefetch DISTANCE 2:
//   batch k lives in reg set (k&1); loaded at iter k-3, ds_written to
//   LDS[k&1] at iter k-1, consumed at iter k. Load->write slack = 2 iters
//   (~1400 wave-cyc) covers L3/HBM latency. Still exactly 2 reg sets.
// LDS layouts (round-2/6 verified): Wl[buf][ki][arr][o*8+fq] lane l writes
// [arr=w][l]; Hl lane l writes (w&1)*64+l; wave w stages ki=w>>1.
__device__ __forceinline__ void cmadd4(float (&are)[4], float (&aim)[4],
                                       const float4 hA, const float4 hB,
                                       const float4 wr, const float4 wi) {
    are[0] += hA.x * wr.x - hA.y * wi.x;  aim[0] += hA.x * wi.x + hA.y * wr.x;
    are[1] += hA.z * wr.y - hA.w * wi.y;  aim[1] += hA.z * wi.y + hA.w * wr.y;
    are[2] += hB.x * wr.z - hB.y * wi.z;  aim[2] += hB.x * wi.z + hB.y * wr.z;
    are[3] += hB.z * wr.w - hB.w * wi.w;  aim[3] += hB.z * wi.w + hB.w * wr.w;
}

__global__ __launch_bounds__(256) void k_pw2(const float2* __restrict__ Hf,
                                             const float* __restrict__ wzr,
                                             const float* __restrict__ wzi,
                                             const float* __restrict__ wrr,
                                             const float* __restrict__ wri,
                                             float2* __restrict__ Zf,
                                             float2* __restrict__ Rf) {
    __shared__ float4 Wl[2][2][4][64];   // 16 KB
    __shared__ float4 Hl[2][2][8][16];   //  8 KB
    const int t  = threadIdx.x;
    const int l  = t & 63, w = t >> 6;       // lane, wave
    const int fq = t & 7,  og = (t >> 3) & 7;
    const int o  = blockIdx.y * 8 + og;
    const int b0 = blockIdx.z * 8 + w * 2;
    const int fA = blockIdx.x * 32 + fq * 4;
    const size_t wstep = (size_t)64 * NFREQ;

    // staging source bases (per-lane global addresses, round-2 maps)
    const int o_l = l >> 3, fq_l = l & 7;
    const float* wa = (w == 0) ? wzr : (w == 1) ? wzi : (w == 2) ? wrr : wri;
    const float* wsrc = wa + (size_t)(blockIdx.y * 8 + o_l) * NFREQ
                           + blockIdx.x * 32 + fq_l * 4;
    const int ski = w >> 1;                   // Hf ki staged by this wave
    const int sb  = (w & 1) * 4 + (l >> 4);   // local b staged by this lane
    const float2* hsrc = Hf + (size_t)((blockIdx.z * 8 + sb) * 64) * NFREQ
                            + blockIdx.x * 32 + (l & 15) * 2;

    float4 aw0, aw1, ah;   // reg set A (even batches)
    float4 bw0, bw1, bh;   // reg set B (odd batches)

#define LOADB(ii, r0, r1, rh_) do {                                            \
        r0  = *(const float4*)(wsrc + (size_t)(2 * (ii)) * wstep);             \
        r1  = *(const float4*)(wsrc + (size_t)(2 * (ii) + 1) * wstep);         \
        rh_ = *(const float4*)(hsrc + (size_t)(2 * (ii) + ski) * NFREQ);       \
    } while (0)
#define WRITEB(bf, r0, r1, rh_) do {                                           \
        Wl[bf][0][w][l] = r0;                                                  \
        Wl[bf][1][w][l] = r1;                                                  \
        (&Hl[bf][ski][0][0])[(w & 1) * 64 + l] = rh_;                          \
    } while (0)
#define COMP(bf) do {                                                          \
        _Pragma("unroll")                                                      \
        for (int ki = 0; ki < 2; ++ki) {                                       \
            const float4 vzr = Wl[bf][ki][0][og * 8 + fq];                     \
            const float4 vzi = Wl[bf][ki][1][og * 8 + fq];                     \
            const float4 vrr = Wl[bf][ki][2][og * 8 + fq];                     \
            const float4 vri = Wl[bf][ki][3][og * 8 + fq];                     \
            _Pragma("unroll")                                                  \
            for (int bb = 0; bb < 2; ++bb) {                                   \
                const float4 hA = Hl[bf][ki][w * 2 + bb][2 * fq];              \
                const float4 hB = Hl[bf][ki][w * 2 + bb][2 * fq + 1];          \
                cmadd4(zre[bb], zim[bb], hA, hB, vzr, vzi);                    \
                cmadd4(rre[bb], rim[bb], hA, hB, vrr, vri);                    \
            }                                                                  \
        }                                                                      \
    } while (0)

    float zre[2][4], zim[2][4], rre[2][4], rim[2][4];
#pragma unroll
    for (int b = 0; b < 2; ++b)
#pragma unroll
        for (int k = 0; k < 4; ++k) {
            zre[b][k] = 0.0f; zim[b][k] = 0.0f;
            rre[b][k] = 0.0f; rim[b][k] = 0.0f;
        }

    // prologue: batch0 -> LDS0 (via A); batch1 -> B; batch2 -> A (in flight)
    LOADB(0, aw0, aw1, ah);
    WRITEB(0, aw0, aw1, ah);
    LOADB(1, bw0, bw1, bh);
    LOADB(2, aw0, aw1, ah);
    __syncthreads();

    for (int s = 0; s < 32; s += 2) {
        // iter s (even): B holds batch s+1 -> LDS[1]; load batch s+3 -> B
        WRITEB(1, bw0, bw1, bh);
        if (s < 29) LOADB(s + 3, bw0, bw1, bh);
        COMP(0);
        __syncthreads();
        // iter s+1 (odd): A holds batch s+2 -> LDS[0]; load batch s+4 -> A
        if (s < 30) WRITEB(0, aw0, aw1, ah);
        if (s < 28) LOADB(s + 4, aw0, aw1, ah);
        COMP(1);
        __syncthreads();
    }
#undef LOADB
#undef WRITEB
#undef COMP

#pragma unroll
    for (int b = 0; b < 2; ++b) {
        float4* pz = (float4*)(Zf + (size_t)((b0 + b) * 64 + o) * NFREQ + fA);
        float4* pr = (float4*)(Rf + (size_t)((b0 + b) * 64 + o) * NFREQ + fA);
        pz[0] = make_float4(zre[b][0], zim[b][0], zre[b][1], zim[b][1]);
        pz[1] = make_float4(zre[b][2], zim[b][2], zre[b][3], zim[b][3]);
        pr[0] = make_float4(rre[b][0], rim[b][0], rre[b][1], rim[b][1]);
        pr[1] = make_float4(rre[b][2], rim[b][2], rre[b][3], rim[b][3]);
    }
}

__global__ __launch_bounds__(256) void k_pw1(const float2* __restrict__ Hf,
                                             const float* __restrict__ whr,
                                             const float* __restrict__ whi,
                                             float2* __restrict__ Of) {
    __shared__ float4 Wl[2][2][2][64];   // 8 KB
    __shared__ float4 Hl[2][2][8][16];   // 8 KB
    const int t  = threadIdx.x;
    const int l  = t & 63, w = t >> 6;
    const int fq = t & 7,  og = (t >> 3) & 7;
    const int o  = blockIdx.y * 8 + og;
    const int b0 = blockIdx.z * 8 + w * 2;
    const int fA = blockIdx.x * 32 + fq * 4;
    const size_t wstep = (size_t)64 * NFREQ;

    // wave w stages weight (ki=w>>1, arr=w&1) and Hf (ki=w>>1, half=w&1)
    const int o_l = l >> 3, fq_l = l & 7;
    const int ski = w >> 1, warr = w & 1;
    const float* wa = warr ? whi : whr;
    const float* wsrc = wa + (size_t)(blockIdx.y * 8 + o_l) * NFREQ
                           + blockIdx.x * 32 + fq_l * 4;
    const int sb  = (w & 1) * 4 + (l >> 4);
    const float2* hsrc = Hf + (size_t)((blockIdx.z * 8 + sb) * 64) * NFREQ
                            + blockIdx.x * 32 + (l & 15) * 2;

    float4 aw, ah;   // reg set A (even batches)
    float4 bw, bh;   // reg set B (odd batches)

#define LOADB(ii, r0, rh_) do {                                                \
        r0  = *(const float4*)(wsrc + (size_t)(2 * (ii) + ski) * wstep);       \
        rh_ = *(const float4*)(hsrc + (size_t)(2 * (ii) + ski) * NFREQ);       \
    } while (0)
#define WRITEB(bf, r0, rh_) do {                                               \
        Wl[bf][ski][warr][l] = r0;                                             \
        (&Hl[bf][ski][0][0])[(w & 1) * 64 + l] = rh_;                          \
    } while (0)
#define COMP(bf) do {                                                          \
        _Pragma("unroll")                                                      \
        for (int ki = 0; ki < 2; ++ki) {                                       \
            const float4 vr = Wl[bf][ki][0][og * 8 + fq];                      \
            const float4 vi = Wl[bf][ki][1][og * 8 + fq];                      \
            _Pragma("unroll")                                                  \
            for (int bb = 0; bb < 2; ++bb) {                                   \
                const float4 hA = Hl[bf][ki][w * 2 + bb][2 * fq];              \
                const float4 hB = Hl[bf][ki][w * 2 + bb][2 * fq + 1];          \
                cmadd4(cre[bb], cim[bb], hA, hB, vr, vi);                      \
            }                                                                  \
        }                                                                      \
    } while (0)

    float cre[2][4], cim[2][4];
#pragma unroll
    for (int b = 0; b < 2; ++b)
#pragma unroll
        for (int k = 0; k < 4; ++k) { cre[b][k] = 0.0f; cim[b][k] = 0.0f; }

    LOADB(0, aw, ah);
    WRITEB(0, aw, ah);
    LOADB(1, bw, bh);
    LOADB(2, aw, ah);
    __syncthreads();

    for (int s = 0; s < 32; s += 2) {
        WRITEB(1, bw, bh);
        if (s < 29) LOADB(s + 3, bw, bh);
        COMP(0);
        __syncthreads();
        if (s < 30) WRITEB(0, aw, ah);
        if (s < 28) LOADB(s + 4, aw, ah);
        COMP(1);
        __syncthreads();
    }
#undef LOADB
#undef WRITEB
#undef COMP

#pragma unroll
    for (int b = 0; b < 2; ++b) {
        float4* po = (float4*)(Of + (size_t)((b0 + b) * 64 + o) * NFREQ + fA);
        po[0] = make_float4(cre[b][0], cim[b][0], cre[b][1], cim[b][1]);
        po[1] = make_float4(cre[b][2], cim[b][2], cre[b][3], cim[b][3]);
    }
}

// ---------------- y = h @ Wo + bo, per step --------------------------------
__global__ __launch_bounds__(256) void k_yproj(const float* __restrict__ h,
                                               const float* __restrict__ Wo,
                                               const float* __restrict__ bo,
                                               float* __restrict__ out,
                                               int step) {
    __shared__ float wo[64];
    const int t = threadIdx.x;
    if (t < 64) wo[t] = Wo[t];
    __syncthreads();
    const int b = blockIdx.x >> 4, xg = blockIdx.x & 15;
    const int xx = xg * 4 + (t >> 6), y = t & 63;
    const float* hp = h + (size_t)b * 64 * IMGSZ + xx * 64 + y;
    float acc = bo[0];
#pragma unroll 8
    for (int c = 0; c < 64; ++c) acc += hp[(size_t)c * IMGSZ] * wo[c];
    out[((size_t)b * 20 + step) * IMGSZ + xx * 64 + y] = acc;
}

// ---------------------------------------------------------------------------
extern "C" void kernel_launch(void* const* d_in, const int* in_sizes, int n_in,
                              void* d_out, int out_size, void* d_ws, size_t ws_size,
                              hipStream_t stream) {
    const float* x    = (const float*)d_in[0];
    // d_in[1] = num_time_steps (always 20 per setup_inputs)
    const float* Wi   = (const float*)d_in[2];
    const float* bi   = (const float*)d_in[3];
    const float* Wo   = (const float*)d_in[4];
    const float* bo   = (const float*)d_in[5];
    const float* Wz_r = (const float*)d_in[6];
    const float* Wz_i = (const float*)d_in[7];
    const float* Wr_r = (const float*)d_in[8];
    const float* Wr_i = (const float*)d_in[9];
    const float* Wh_r = (const float*)d_in[10];
    const float* Wh_i = (const float*)d_in[11];

    float* ws = (float*)d_ws;
    float* h = ws;                              // 4,194,304 floats
    float2* B0 = (float2*)(ws + 4194304);       // 2,162,688 float2 each
    float2* B1 = B0 + 2162688;
    float2* B2 = B1 + 2162688;
    float* outp = (float*)d_out;

    k_h0fft<<<NIMG, 64, 0, stream>>>(x, Wi, bi, h, B0);   // h0, Hf -> B0

    for (int t = 0; t < 20; ++t) {
        k_pw2<<<dim3(66, 8, 2), 256, 0, stream>>>(B0, Wz_r, Wz_i, Wr_r, Wr_i,
                                                  B1, B2);  // Zf->B1 Rf->B2
        k_fifft_r<<<NIMG, 64, 0, stream>>>(B2, h, B2);      // RHf -> B2
        k_pw1<<<dim3(66, 8, 2), 256, 0, stream>>>(B2, Wh_r, Wh_i, B0); // Nf->B0
        k_fifft_n<<<NIMG, 64, 0, stream>>>(B0, B1, h, B0);  // h, Hf_next -> B0
        k_yproj<<<256, 256, 0, stream>>>(h, Wo, bo, outp, t);
    }
}